// Round 6
// baseline (369.580 us; speedup 1.0000x reference)
//
#include <hip/hip_runtime.h>
#include <stdint.h>

#define BATCH 8
#define NANCH 32768
#define NCLS 81
#define PRE_K 2048
#define MAX_OUT 200
#define IOU_TH 0.5f
#define SCORE_TH 0.05f

typedef uint32_t u32;
typedef uint64_t u64;
typedef uint8_t u8;

// monotone float->u32 (order-preserving)
__device__ __forceinline__ u32 f2sort(float f) {
  u32 u = __float_as_uint(f);
  return (u & 0x80000000u) ? ~u : (u | 0x80000000u);
}
__device__ __forceinline__ float sort2f(u32 u) {
  u = (u & 0x80000000u) ? (u & 0x7FFFFFFFu) : ~u;
  return __uint_as_float(u);
}

// ---------------- kernel 1: per-anchor max/argmax over 81 classes ----------
__global__ __launch_bounds__(256) void k_score(const float* __restrict__ confs,
                                               u64* __restrict__ keys,
                                               u8* __restrict__ cats) {
  __shared__ float st[64 * NCLS];  // 20.25 KB
  __shared__ u64 outk[64];
  __shared__ u8 outc[64];
  int tid = threadIdx.x;
  const float4* src = (const float4*)confs + (size_t)blockIdx.x * (64 * NCLS / 4);
  float4* dst = (float4*)st;
  for (int idx = tid; idx < 64 * NCLS / 4; idx += 256) dst[idx] = src[idx];
  __syncthreads();

  int a = tid >> 2, s = tid & 3;
  const float* row = st + a * NCLS;
  int c0 = s * 20;
  int cnt = (s == 3) ? 21 : 20;
  u64 key = 0;
  for (int k = 0; k < cnt; ++k) {
    int c = c0 + k;
    u64 k2 = ((u64)__float_as_uint(row[c]) << 7) | (u32)(127 - c);
    if (k2 > key) key = k2;
  }
  u64 o = __shfl_xor(key, 1); if (o > key) key = o;
  o = __shfl_xor(key, 2); if (o > key) key = o;
  if (s == 0) {
    float v = __uint_as_float((u32)(key >> 7));
    int c = 127 - (int)(key & 127);
    int n = (blockIdx.x * 64 + a) & (NANCH - 1);
    bool valid = (v > SCORE_TH) && (c != 0);
    float sc = valid ? v : -1.0f;
    outk[a] = ((u64)f2sort(sc) << 32) | (u64)(0xFFFFFFFFu - (u32)n);
    outc[a] = (u8)c;
  }
  __syncthreads();
  if (tid < 64) {
    int g = blockIdx.x * 64 + tid;
    keys[g] = outk[tid];
    cats[g] = outc[tid];
  }
}

// -------- wave-scan digit finder: 2 barriers, wave 0 does the scan ---------
// bins scanned in DESCENDING order; finds D with suffix(D) >= need > suffix(D+1)
template <int B>
__device__ void scan_digit_fast(const u32* gh, int need, u32* sbuf,
                                int tid, int* D, int* NO) {
  const int CS = B / 256;  // bins per chunk
  if (tid < 256) {
    int hi = B - 1 - tid * CS;
    u32 s = 0;
    #pragma unroll 4
    for (int k = 0; k < CS; ++k) s += gh[hi - k];
    sbuf[tid] = s;
  }
  __syncthreads();
  if (tid < 64) {
    u32 v0 = sbuf[tid * 4], v1 = sbuf[tid * 4 + 1];
    u32 v2 = sbuf[tid * 4 + 2], v3 = sbuf[tid * 4 + 3];
    u32 loc = v0 + v1 + v2 + v3;
    u32 inc = loc;
    #pragma unroll
    for (int off = 1; off < 64; off <<= 1) {
      u32 ov = __shfl_up(inc, off);
      if (tid >= off) inc += ov;
    }
    u32 exc = inc - loc;
    if (exc < (u32)need && inc >= (u32)need) {  // unique lane
      int acc = (int)exc;
      u32 vs[4] = {v0, v1, v2, v3};
      #pragma unroll
      for (int c = 0; c < 4; ++c) {
        if (acc + (int)vs[c] >= need) {
          int h2 = B - 1 - (tid * 4 + c) * CS;
          for (int k = 0; k < CS; ++k) {
            u32 h = gh[h2 - k];
            acc += (int)h;
            if (acc >= need) {
              sbuf[256] = (u32)(h2 - k);
              sbuf[257] = (u32)(need - (acc - (int)h));
              break;
            }
          }
          break;
        }
        acc += (int)vs[c];
      }
    }
  }
  __syncthreads();
  *D = (int)sbuf[256];
  *NO = (int)sbuf[257];
  __syncthreads();
}

// ---------------- kernel 2: fused select+compact+rank+emit, 1 WG/batch -----
__global__ __launch_bounds__(1024) void k_sel(const u64* __restrict__ keys,
                                              const u8* __restrict__ cats,
                                              const float* __restrict__ boxes,
                                              float4* __restrict__ candOff,
                                              float4* __restrict__ candOrig,
                                              float* __restrict__ candScore,
                                              int* __restrict__ candCat) {
  int b = blockIdx.x;
  int tid = threadIdx.x;
  int lane = tid & 63;
  __shared__ u32 hist[4096];   // 16 KB
  __shared__ u32 sbuf[258];
  __shared__ u64 selk[PRE_K];  // 16 KB
  __shared__ u64 ties[128];
  __shared__ u32 s_cnt, s_tcnt;

  const u64* bk = keys + (size_t)b * NANCH;
  u64 kk[32];
  #pragma unroll
  for (int i = 0; i < 32; ++i) kk[i] = bk[tid + i * 1024];

  if (tid == 0) { s_cnt = 0; s_tcnt = 0; }
  for (int i = tid; i < 4096; i += 1024) hist[i] = 0;
  __syncthreads();

  // ---- pass 1: top 8 bits, warp-aggregated (distribution is concentrated)
  #pragma unroll 4
  for (int i = 0; i < 32; ++i) {
    u32 d = (u32)(kk[i] >> 56);
    u64 todo = ~0ull;  // all lanes active
    while (todo) {
      int src = __ffsll((unsigned long long)todo) - 1;
      u32 dd = __shfl(d, src);
      u64 match = __ballot(d == dd);
      if (lane == src) atomicAdd(&hist[dd], (u32)__popcll(match));
      todo &= ~match;
    }
  }
  __syncthreads();
  int D1, n1;
  scan_digit_fast<256>(hist, PRE_K, sbuf, tid, &D1, &n1);

  for (int i = tid; i < 4096; i += 1024) hist[i] = 0;
  __syncthreads();

  // ---- pass 2: next 12 bits, warp-aggregated
  u32 p1 = (u32)D1;
  #pragma unroll 4
  for (int i = 0; i < 32; ++i) {
    u32 h = (u32)(kk[i] >> 32);
    bool act = (h >> 24) == p1;
    u32 d = (h >> 12) & 0xFFF;
    u64 todo = __ballot(act);
    while (todo) {
      int src = __ffsll((unsigned long long)todo) - 1;
      u32 dd = __shfl(d, src);
      u64 match = __ballot(act && d == dd);
      if (lane == src) atomicAdd(&hist[dd], (u32)__popcll(match));
      todo &= ~match;
    }
  }
  __syncthreads();
  int D2, n2;
  scan_digit_fast<4096>(hist, n1, sbuf, tid, &D2, &n2);

  for (int i = tid; i < 4096; i += 1024) hist[i] = 0;
  __syncthreads();

  // ---- pass 3: low 12 bits, plain atomics (spread over 4096 bins)
  u32 p2 = (p1 << 12) | (u32)D2;
  #pragma unroll 4
  for (int i = 0; i < 32; ++i) {
    u32 h = (u32)(kk[i] >> 32);
    if ((h >> 12) == p2) atomicAdd(&hist[h & 0xFFF], 1u);
  }
  __syncthreads();
  int D3, n3;
  scan_digit_fast<4096>(hist, n2, sbuf, tid, &D3, &n3);

  u32 S32 = (p2 << 12) | (u32)D3;
  int need3 = n3;

  // ---- compaction from registers into LDS (wave-aggregated counter)
  #pragma unroll 4
  for (int i = 0; i < 32; ++i) {
    u64 k = kk[i];
    u32 k32 = (u32)(k >> 32);
    bool gt = k32 > S32;
    u64 m = __ballot(gt);
    u32 wbase = 0;
    if (lane == 0 && m) wbase = atomicAdd(&s_cnt, (u32)__popcll(m));
    wbase = __shfl(wbase, 0);
    if (gt) {
      u32 pos = wbase + (u32)__popcll(m & ((1ull << lane) - 1));
      if (pos < PRE_K) selk[pos] = k;
    }
    if (k32 == S32) {
      u32 tp = atomicAdd(&s_tcnt, 1u);
      if (tp < 128) ties[tp] = k;
    }
  }
  __syncthreads();

  // ---- boundary-tie resolve
  int nt = (int)s_tcnt; if (nt > 128) nt = 128;
  int base = (int)s_cnt;  // == PRE_K - need3
  if (tid < nt) {
    u64 my = ties[tid];
    int r = 0;
    for (int j = 0; j < nt; ++j) r += (ties[j] > my);
    if (r < need3 && base + r < PRE_K) selk[base + r] = my;
  }
  __syncthreads();

  // ---- rank-by-count + gather + emit (2 candidates per thread)
  for (int idx = tid; idx < PRE_K; idx += 1024) {
    u64 my = selk[idx];
    int rank = 0;
    #pragma unroll 8
    for (int j = 0; j < PRE_K; ++j) rank += (selk[j] > my);
    u32 n = 0xFFFFFFFFu - (u32)(my & 0xFFFFFFFFu);
    float s = sort2f((u32)(my >> 32));
    int cat = (int)cats[(size_t)b * NANCH + n];
    const float* bp = boxes + ((size_t)b * NANCH + n) * 4;
    float4 ob = make_float4(bp[0], bp[1], bp[2], bp[3]);
    float off = 2.0f * (float)cat;
    float4 obo = make_float4(ob.x + off, ob.y + off, ob.z + off, ob.w + off);
    int o = b * PRE_K + rank;
    candOff[o] = obo;
    candOrig[o] = ob;
    candScore[o] = s;
    candCat[o] = cat;
  }
}

// ---------------- 2048x2048 upper-triangle suppression bitmask -------------
__global__ __launch_bounds__(256) void k_mask(const float4* __restrict__ candOff,
                                              u64* __restrict__ mask) {
  int b = blockIdx.y;
  int tid = threadIdx.x;
  int wave = tid >> 6, lane = tid & 63;
  __shared__ float4 sb[PRE_K];   // 32 KB
  __shared__ float sarea[PRE_K]; // 8 KB
  for (int j = tid; j < PRE_K; j += 256) {
    float4 v = candOff[b * PRE_K + j];
    sb[j] = v;
    sarea[j] = fmaxf(v.z - v.x, 0.0f) * fmaxf(v.w - v.y, 0.0f);
  }
  __syncthreads();

  int gw = blockIdx.x * 4 + wave;
  for (int k = 0; k < PRE_K / 256; ++k) {
    int i = gw + 256 * k;
    float4 bi = sb[i];
    float ai = sarea[i];
    int c0 = i >> 6;
    u64 myword = 0;
    for (int c = c0; c < 32; ++c) {
      float4 bj = sb[c * 64 + lane];
      float aj = sarea[c * 64 + lane];
      float lx = fmaxf(bi.x, bj.x), ly = fmaxf(bi.y, bj.y);
      float rx = fminf(bi.z, bj.z), ry = fminf(bi.w, bj.w);
      float iw = fmaxf(rx - lx, 0.0f), ih = fmaxf(ry - ly, 0.0f);
      float inter = iw * ih;
      float uni = fmaxf(ai + aj - inter, 1e-9f);
      u64 word = __ballot(inter > 0.5f * uni);
      if (lane == c) myword = word;
    }
    if (lane < 32) mask[((size_t)(b * PRE_K + i)) * 32 + lane] = myword;
  }
}

// ---------------- greedy scan + output (8-deep row prefetch) ---------------
__global__ __launch_bounds__(64) void k_scan(const u64* __restrict__ mask,
                                             const float4* __restrict__ candOrig,
                                             const float* __restrict__ candScore,
                                             const int* __restrict__ candCat,
                                             float* __restrict__ out) {
  int b = blockIdx.x;
  int tid = threadIdx.x;
  __shared__ float ssc[PRE_K];
  __shared__ int keptI[MAX_OUT];
  for (int j = tid; j < PRE_K; j += 64) ssc[j] = candScore[b * PRE_K + j];
  __syncthreads();

  const u64* mrow = mask + (size_t)b * PRE_K * 32;
  int wsel = tid & 31;
  bool lo32 = tid < 32;
  u64 remv = 0;
  int cnt = 0;

  u64 c0=0,c1=0,c2=0,c3=0,c4=0,c5=0,c6=0,c7=0;
  if (lo32) {
    c0 = mrow[0 * 32 + wsel]; c1 = mrow[1 * 32 + wsel];
    c2 = mrow[2 * 32 + wsel]; c3 = mrow[3 * 32 + wsel];
    c4 = mrow[4 * 32 + wsel]; c5 = mrow[5 * 32 + wsel];
    c6 = mrow[6 * 32 + wsel]; c7 = mrow[7 * 32 + wsel];
  }

#define PROCESS(I, RK)                                   \
  {                                                      \
    u64 wb = __shfl(remv, (I) >> 6);                     \
    bool sup = (wb >> ((I) & 63)) & 1ull;                \
    if (!sup && ssc[I] > SCORE_TH) {                     \
      if (tid == 0 && cnt < MAX_OUT) keptI[cnt] = (I);   \
      if (lo32) remv |= (RK);                            \
      cnt++;                                             \
    }                                                    \
  }

  for (int base = 0; base < PRE_K; base += 8) {
    u64 n0=0,n1=0,n2=0,n3=0,n4=0,n5=0,n6=0,n7=0;
    if (base + 8 < PRE_K && lo32) {
      const u64* nr = mrow + (size_t)(base + 8) * 32 + wsel;
      n0 = nr[0 * 32]; n1 = nr[1 * 32]; n2 = nr[2 * 32]; n3 = nr[3 * 32];
      n4 = nr[4 * 32]; n5 = nr[5 * 32]; n6 = nr[6 * 32]; n7 = nr[7 * 32];
    }
    PROCESS(base + 0, c0); PROCESS(base + 1, c1);
    PROCESS(base + 2, c2); PROCESS(base + 3, c3);
    PROCESS(base + 4, c4); PROCESS(base + 5, c5);
    PROCESS(base + 6, c6); PROCESS(base + 7, c7);
    c0=n0; c1=n1; c2=n2; c3=n3; c4=n4; c5=n5; c6=n6; c7=n7;
    if (cnt >= MAX_OUT) break;
  }
#undef PROCESS

  int kc = cnt < MAX_OUT ? cnt : MAX_OUT;
  __syncthreads();

  float* out5 = out;
  float* ocat = out + BATCH * MAX_OUT * 5;
  for (int r = tid; r < MAX_OUT; r += 64) {
    float* p = out5 + ((size_t)(b * MAX_OUT + r)) * 5;
    if (r < kc) {
      int i = keptI[r];
      float4 ob = candOrig[b * PRE_K + i];
      p[0] = ob.x; p[1] = ob.y; p[2] = ob.z; p[3] = ob.w; p[4] = ssc[i];
      ocat[b * MAX_OUT + r] = (float)candCat[b * PRE_K + i];
    } else {
      p[0] = 0.0f; p[1] = 0.0f; p[2] = 0.0f; p[3] = 0.0f; p[4] = 0.0f;
      ocat[b * MAX_OUT + r] = 0.0f;
    }
  }
}

extern "C" void kernel_launch(void* const* d_in, const int* in_sizes, int n_in,
                              void* d_out, int out_size, void* d_ws, size_t ws_size,
                              hipStream_t stream) {
  const float* boxes = (const float*)d_in[0];
  const float* confs = (const float*)d_in[1];
  float* out = (float*)d_out;
  char* ws = (char*)d_ws;

  const size_t OFF_KEYS = 0;                            // 2 MB
  const size_t OFF_CATS = (size_t)2 << 20;              // 256 KB (u8)
  const size_t OFF_COFF = OFF_CATS + (256u << 10);      // 256 KB
  const size_t OFF_CORG = OFF_COFF + (256u << 10);      // 256 KB
  const size_t OFF_CSC  = OFF_CORG + (256u << 10);      // 64 KB
  const size_t OFF_CCAT = OFF_CSC + (64u << 10);        // 64 KB
  const size_t OFF_MASK = OFF_CCAT + (64u << 10);       // 4 MB

  u64* keys    = (u64*)(ws + OFF_KEYS);
  u8* cats     = (u8*)(ws + OFF_CATS);
  float4* cOff = (float4*)(ws + OFF_COFF);
  float4* cOrg = (float4*)(ws + OFF_CORG);
  float* cSc   = (float*)(ws + OFF_CSC);
  int* cCat    = (int*)(ws + OFF_CCAT);
  u64* mask    = (u64*)(ws + OFF_MASK);

  k_score<<<BATCH * NANCH / 64, 256, 0, stream>>>(confs, keys, cats);
  k_sel<<<BATCH, 1024, 0, stream>>>(keys, cats, boxes, cOff, cOrg, cSc, cCat);
  dim3 g3(64, BATCH);
  k_mask<<<g3, 256, 0, stream>>>(cOff, mask);
  k_scan<<<BATCH, 64, 0, stream>>>(mask, cOrg, cSc, cCat, out);
}

// Round 7
// 356.125 us; speedup vs baseline: 1.0378x; 1.0378x over previous
//
#include <hip/hip_runtime.h>
#include <stdint.h>

#define BATCH 8
#define NANCH 32768
#define NCLS 81
#define PRE_K 2048
#define MAX_OUT 200
#define IOU_TH 0.5f
#define SCORE_TH 0.05f

typedef uint32_t u32;
typedef uint64_t u64;
typedef uint8_t u8;

// monotone float->u32 (order-preserving)
__device__ __forceinline__ u32 f2sort(float f) {
  u32 u = __float_as_uint(f);
  return (u & 0x80000000u) ? ~u : (u | 0x80000000u);
}
__device__ __forceinline__ float sort2f(u32 u) {
  u = (u & 0x80000000u) ? (u & 0x7FFFFFFFu) : ~u;
  return __uint_as_float(u);
}

// ---------------- kernel 1: per-anchor max/argmax over 81 classes ----------
__global__ __launch_bounds__(256) void k_score(const float* __restrict__ confs,
                                               u64* __restrict__ keys,
                                               u8* __restrict__ cats) {
  __shared__ float st[64 * NCLS];  // 20.25 KB
  __shared__ u64 outk[64];
  __shared__ u8 outc[64];
  int tid = threadIdx.x;
  const float4* src = (const float4*)confs + (size_t)blockIdx.x * (64 * NCLS / 4);
  float4* dst = (float4*)st;
  for (int idx = tid; idx < 64 * NCLS / 4; idx += 256) dst[idx] = src[idx];
  __syncthreads();

  int a = tid >> 2, s = tid & 3;
  const float* row = st + a * NCLS;
  int c0 = s * 20;
  int cnt = (s == 3) ? 21 : 20;
  u64 key = 0;
  for (int k = 0; k < cnt; ++k) {
    int c = c0 + k;
    u64 k2 = ((u64)__float_as_uint(row[c]) << 7) | (u32)(127 - c);
    if (k2 > key) key = k2;
  }
  u64 o = __shfl_xor(key, 1); if (o > key) key = o;
  o = __shfl_xor(key, 2); if (o > key) key = o;
  if (s == 0) {
    float v = __uint_as_float((u32)(key >> 7));
    int c = 127 - (int)(key & 127);
    int n = (blockIdx.x * 64 + a) & (NANCH - 1);
    bool valid = (v > SCORE_TH) && (c != 0);
    float sc = valid ? v : -1.0f;
    outk[a] = ((u64)f2sort(sc) << 32) | (u64)(0xFFFFFFFFu - (u32)n);
    outc[a] = (u8)c;
  }
  __syncthreads();
  if (tid < 64) {
    int g = blockIdx.x * 64 + tid;
    keys[g] = outk[tid];
    cats[g] = outc[tid];
  }
}

// -------- wave-scan digit finder: 2 barriers, wave 0 does the scan ---------
template <int B>
__device__ void scan_digit_fast(const u32* gh, int need, u32* sbuf,
                                int tid, int* D, int* NO) {
  const int CS = B / 256;
  if (tid < 256) {
    int hi = B - 1 - tid * CS;
    u32 s = 0;
    #pragma unroll 4
    for (int k = 0; k < CS; ++k) s += gh[hi - k];
    sbuf[tid] = s;
  }
  __syncthreads();
  if (tid < 64) {
    u32 v0 = sbuf[tid * 4], v1 = sbuf[tid * 4 + 1];
    u32 v2 = sbuf[tid * 4 + 2], v3 = sbuf[tid * 4 + 3];
    u32 loc = v0 + v1 + v2 + v3;
    u32 inc = loc;
    #pragma unroll
    for (int off = 1; off < 64; off <<= 1) {
      u32 ov = __shfl_up(inc, off);
      if (tid >= off) inc += ov;
    }
    u32 exc = inc - loc;
    if (exc < (u32)need && inc >= (u32)need) {  // unique lane
      int acc = (int)exc;
      u32 vs[4] = {v0, v1, v2, v3};
      #pragma unroll
      for (int c = 0; c < 4; ++c) {
        if (acc + (int)vs[c] >= need) {
          int h2 = B - 1 - (tid * 4 + c) * CS;
          for (int k = 0; k < CS; ++k) {
            u32 h = gh[h2 - k];
            acc += (int)h;
            if (acc >= need) {
              sbuf[256] = (u32)(h2 - k);
              sbuf[257] = (u32)(need - (acc - (int)h));
              break;
            }
          }
          break;
        }
        acc += (int)vs[c];
      }
    }
  }
  __syncthreads();
  *D = (int)sbuf[256];
  *NO = (int)sbuf[257];
  __syncthreads();
}

// ---------------- kernel 2: fused select+compact+rank+emit, 1 WG/batch -----
// Keys streamed from global each pass (L2-resident 256 KB/WG); no register
// arrays (avoids scratch spill), warp-aggregated hist for concentrated bins.
__global__ __launch_bounds__(1024) void k_sel(const u64* __restrict__ keys,
                                              const u8* __restrict__ cats,
                                              const float* __restrict__ boxes,
                                              float4* __restrict__ candOff,
                                              float4* __restrict__ candOrig,
                                              float* __restrict__ candScore,
                                              int* __restrict__ candCat) {
  int b = blockIdx.x;
  int tid = threadIdx.x;
  int lane = tid & 63;
  __shared__ u32 hist[4096];   // 16 KB
  __shared__ u32 sbuf[258];
  __shared__ u64 selk[PRE_K];  // 16 KB
  __shared__ u64 ties[128];
  __shared__ u32 s_cnt, s_tcnt;

  const u64* bk = keys + (size_t)b * NANCH;

  if (tid == 0) { s_cnt = 0; s_tcnt = 0; }
  for (int i = tid; i < 4096; i += 1024) hist[i] = 0;
  __syncthreads();

  // ---- pass 1: top 8 bits, warp-aggregated (distribution is concentrated)
  for (int i = tid; i < NANCH; i += 1024) {
    u32 d = (u32)(bk[i] >> 56);
    u64 todo = ~0ull;
    while (todo) {
      int src = __ffsll((unsigned long long)todo) - 1;
      u32 dd = __shfl(d, src);
      u64 match = __ballot(d == dd);
      if (lane == src) atomicAdd(&hist[dd], (u32)__popcll(match));
      todo &= ~match;
    }
  }
  __syncthreads();
  int D1, n1;
  scan_digit_fast<256>(hist, PRE_K, sbuf, tid, &D1, &n1);

  for (int i = tid; i < 4096; i += 1024) hist[i] = 0;
  __syncthreads();

  // ---- pass 2: next 12 bits, warp-aggregated
  u32 p1 = (u32)D1;
  for (int i = tid; i < NANCH; i += 1024) {
    u32 h = (u32)(bk[i] >> 32);
    bool act = (h >> 24) == p1;
    u32 d = (h >> 12) & 0xFFF;
    u64 todo = __ballot(act);
    while (todo) {
      int src = __ffsll((unsigned long long)todo) - 1;
      u32 dd = __shfl(d, src);
      u64 match = __ballot(act && d == dd);
      if (lane == src) atomicAdd(&hist[dd], (u32)__popcll(match));
      todo &= ~match;
    }
  }
  __syncthreads();
  int D2, n2;
  scan_digit_fast<4096>(hist, n1, sbuf, tid, &D2, &n2);

  for (int i = tid; i < 4096; i += 1024) hist[i] = 0;
  __syncthreads();

  // ---- pass 3: low 12 bits, plain atomics (spread over 4096 bins)
  u32 p2 = (p1 << 12) | (u32)D2;
  for (int i = tid; i < NANCH; i += 1024) {
    u32 h = (u32)(bk[i] >> 32);
    if ((h >> 12) == p2) atomicAdd(&hist[h & 0xFFF], 1u);
  }
  __syncthreads();
  int D3, n3;
  scan_digit_fast<4096>(hist, n2, sbuf, tid, &D3, &n3);

  u32 S32 = (p2 << 12) | (u32)D3;
  int need3 = n3;

  // ---- compaction into LDS (wave-aggregated counter)
  for (int i = tid; i < NANCH; i += 1024) {
    u64 k = bk[i];
    u32 k32 = (u32)(k >> 32);
    bool gt = k32 > S32;
    u64 m = __ballot(gt);
    u32 wbase = 0;
    if (lane == 0 && m) wbase = atomicAdd(&s_cnt, (u32)__popcll(m));
    wbase = __shfl(wbase, 0);
    if (gt) {
      u32 pos = wbase + (u32)__popcll(m & ((1ull << lane) - 1));
      if (pos < PRE_K) selk[pos] = k;
    }
    if (k32 == S32) {
      u32 tp = atomicAdd(&s_tcnt, 1u);
      if (tp < 128) ties[tp] = k;
    }
  }
  __syncthreads();

  // ---- boundary-tie resolve
  int nt = (int)s_tcnt; if (nt > 128) nt = 128;
  int base = (int)s_cnt;  // == PRE_K - need3
  if (tid < nt) {
    u64 my = ties[tid];
    int r = 0;
    for (int j = 0; j < nt; ++j) r += (ties[j] > my);
    if (r < need3 && base + r < PRE_K) selk[base + r] = my;
  }
  __syncthreads();

  // ---- rank-by-count + gather + emit (2 candidates per thread)
  for (int idx = tid; idx < PRE_K; idx += 1024) {
    u64 my = selk[idx];
    int rank = 0;
    #pragma unroll 8
    for (int j = 0; j < PRE_K; ++j) rank += (selk[j] > my);
    u32 n = 0xFFFFFFFFu - (u32)(my & 0xFFFFFFFFu);
    float s = sort2f((u32)(my >> 32));
    int cat = (int)cats[(size_t)b * NANCH + n];
    const float* bp = boxes + ((size_t)b * NANCH + n) * 4;
    float4 ob = make_float4(bp[0], bp[1], bp[2], bp[3]);
    float off = 2.0f * (float)cat;
    float4 obo = make_float4(ob.x + off, ob.y + off, ob.z + off, ob.w + off);
    int o = b * PRE_K + rank;
    candOff[o] = obo;
    candOrig[o] = ob;
    candScore[o] = s;
    candCat[o] = cat;
  }
}

// ---------------- 2048x2048 upper-triangle suppression bitmask -------------
__global__ __launch_bounds__(256) void k_mask(const float4* __restrict__ candOff,
                                              u64* __restrict__ mask) {
  int b = blockIdx.y;
  int tid = threadIdx.x;
  int wave = tid >> 6, lane = tid & 63;
  __shared__ float4 sb[PRE_K];   // 32 KB
  __shared__ float sarea[PRE_K]; // 8 KB
  for (int j = tid; j < PRE_K; j += 256) {
    float4 v = candOff[b * PRE_K + j];
    sb[j] = v;
    sarea[j] = fmaxf(v.z - v.x, 0.0f) * fmaxf(v.w - v.y, 0.0f);
  }
  __syncthreads();

  int gw = blockIdx.x * 4 + wave;
  for (int k = 0; k < PRE_K / 256; ++k) {
    int i = gw + 256 * k;
    float4 bi = sb[i];
    float ai = sarea[i];
    int c0 = i >> 6;
    u64 myword = 0;
    for (int c = c0; c < 32; ++c) {
      float4 bj = sb[c * 64 + lane];
      float aj = sarea[c * 64 + lane];
      float lx = fmaxf(bi.x, bj.x), ly = fmaxf(bi.y, bj.y);
      float rx = fminf(bi.z, bj.z), ry = fminf(bi.w, bj.w);
      float iw = fmaxf(rx - lx, 0.0f), ih = fmaxf(ry - ly, 0.0f);
      float inter = iw * ih;
      float uni = fmaxf(ai + aj - inter, 1e-9f);
      u64 word = __ballot(inter > 0.5f * uni);
      if (lane == c) myword = word;
    }
    if (lane < 32) mask[((size_t)(b * PRE_K + i)) * 32 + lane] = myword;
  }
}

// ---------------- greedy scan + output (8-deep row prefetch) ---------------
__global__ __launch_bounds__(64) void k_scan(const u64* __restrict__ mask,
                                             const float4* __restrict__ candOrig,
                                             const float* __restrict__ candScore,
                                             const int* __restrict__ candCat,
                                             float* __restrict__ out) {
  int b = blockIdx.x;
  int tid = threadIdx.x;
  __shared__ float ssc[PRE_K];
  __shared__ int keptI[MAX_OUT];
  for (int j = tid; j < PRE_K; j += 64) ssc[j] = candScore[b * PRE_K + j];
  __syncthreads();

  const u64* mrow = mask + (size_t)b * PRE_K * 32;
  int wsel = tid & 31;
  bool lo32 = tid < 32;
  u64 remv = 0;
  int cnt = 0;

  u64 c0=0,c1=0,c2=0,c3=0,c4=0,c5=0,c6=0,c7=0;
  if (lo32) {
    c0 = mrow[0 * 32 + wsel]; c1 = mrow[1 * 32 + wsel];
    c2 = mrow[2 * 32 + wsel]; c3 = mrow[3 * 32 + wsel];
    c4 = mrow[4 * 32 + wsel]; c5 = mrow[5 * 32 + wsel];
    c6 = mrow[6 * 32 + wsel]; c7 = mrow[7 * 32 + wsel];
  }

#define PROCESS(I, RK)                                   \
  {                                                      \
    u64 wb = __shfl(remv, (I) >> 6);                     \
    bool sup = (wb >> ((I) & 63)) & 1ull;                \
    if (!sup && ssc[I] > SCORE_TH) {                     \
      if (tid == 0 && cnt < MAX_OUT) keptI[cnt] = (I);   \
      if (lo32) remv |= (RK);                            \
      cnt++;                                             \
    }                                                    \
  }

  for (int base = 0; base < PRE_K; base += 8) {
    u64 n0=0,n1=0,n2=0,n3=0,n4=0,n5=0,n6=0,n7=0;
    if (base + 8 < PRE_K && lo32) {
      const u64* nr = mrow + (size_t)(base + 8) * 32 + wsel;
      n0 = nr[0 * 32]; n1 = nr[1 * 32]; n2 = nr[2 * 32]; n3 = nr[3 * 32];
      n4 = nr[4 * 32]; n5 = nr[5 * 32]; n6 = nr[6 * 32]; n7 = nr[7 * 32];
    }
    PROCESS(base + 0, c0); PROCESS(base + 1, c1);
    PROCESS(base + 2, c2); PROCESS(base + 3, c3);
    PROCESS(base + 4, c4); PROCESS(base + 5, c5);
    PROCESS(base + 6, c6); PROCESS(base + 7, c7);
    c0=n0; c1=n1; c2=n2; c3=n3; c4=n4; c5=n5; c6=n6; c7=n7;
    if (cnt >= MAX_OUT) break;
  }
#undef PROCESS

  int kc = cnt < MAX_OUT ? cnt : MAX_OUT;
  __syncthreads();

  float* out5 = out;
  float* ocat = out + BATCH * MAX_OUT * 5;
  for (int r = tid; r < MAX_OUT; r += 64) {
    float* p = out5 + ((size_t)(b * MAX_OUT + r)) * 5;
    if (r < kc) {
      int i = keptI[r];
      float4 ob = candOrig[b * PRE_K + i];
      p[0] = ob.x; p[1] = ob.y; p[2] = ob.z; p[3] = ob.w; p[4] = ssc[i];
      ocat[b * MAX_OUT + r] = (float)candCat[b * PRE_K + i];
    } else {
      p[0] = 0.0f; p[1] = 0.0f; p[2] = 0.0f; p[3] = 0.0f; p[4] = 0.0f;
      ocat[b * MAX_OUT + r] = 0.0f;
    }
  }
}

extern "C" void kernel_launch(void* const* d_in, const int* in_sizes, int n_in,
                              void* d_out, int out_size, void* d_ws, size_t ws_size,
                              hipStream_t stream) {
  const float* boxes = (const float*)d_in[0];
  const float* confs = (const float*)d_in[1];
  float* out = (float*)d_out;
  char* ws = (char*)d_ws;

  const size_t OFF_KEYS = 0;                            // 2 MB
  const size_t OFF_CATS = (size_t)2 << 20;              // 256 KB (u8)
  const size_t OFF_COFF = OFF_CATS + (256u << 10);      // 256 KB
  const size_t OFF_CORG = OFF_COFF + (256u << 10);      // 256 KB
  const size_t OFF_CSC  = OFF_CORG + (256u << 10);      // 64 KB
  const size_t OFF_CCAT = OFF_CSC + (64u << 10);        // 64 KB
  const size_t OFF_MASK = OFF_CCAT + (64u << 10);       // 4 MB

  u64* keys    = (u64*)(ws + OFF_KEYS);
  u8* cats     = (u8*)(ws + OFF_CATS);
  float4* cOff = (float4*)(ws + OFF_COFF);
  float4* cOrg = (float4*)(ws + OFF_CORG);
  float* cSc   = (float*)(ws + OFF_CSC);
  int* cCat    = (int*)(ws + OFF_CCAT);
  u64* mask    = (u64*)(ws + OFF_MASK);

  k_score<<<BATCH * NANCH / 64, 256, 0, stream>>>(confs, keys, cats);
  k_sel<<<BATCH, 1024, 0, stream>>>(keys, cats, boxes, cOff, cOrg, cSc, cCat);
  dim3 g3(64, BATCH);
  k_mask<<<g3, 256, 0, stream>>>(cOff, mask);
  k_scan<<<BATCH, 64, 0, stream>>>(mask, cOrg, cSc, cCat, out);
}

// Round 8
// 198.244 us; speedup vs baseline: 1.8643x; 1.7964x over previous
//
#include <hip/hip_runtime.h>
#include <stdint.h>

#define BATCH 8
#define NANCH 32768
#define NCLS 81
#define PRE_K 2048
#define MAX_OUT 200
#define IOU_TH 0.5f
#define SCORE_TH 0.05f

typedef uint32_t u32;
typedef uint64_t u64;
typedef uint8_t u8;

// monotone float->u32 (order-preserving)
__device__ __forceinline__ u32 f2sort(float f) {
  u32 u = __float_as_uint(f);
  return (u & 0x80000000u) ? ~u : (u | 0x80000000u);
}
__device__ __forceinline__ float sort2f(u32 u) {
  u = (u & 0x80000000u) ? (u & 0x7FFFFFFFu) : ~u;
  return __uint_as_float(u);
}

// ---------------- kernel 1: per-anchor max/argmax over 81 classes ----------
__global__ __launch_bounds__(256) void k_score(const float* __restrict__ confs,
                                               u64* __restrict__ keys,
                                               u32* __restrict__ keyhi,
                                               u8* __restrict__ cats) {
  __shared__ float st[64 * NCLS];  // 20.25 KB
  __shared__ u64 outk[64];
  __shared__ u8 outc[64];
  int tid = threadIdx.x;
  const float4* src = (const float4*)confs + (size_t)blockIdx.x * (64 * NCLS / 4);
  float4* dst = (float4*)st;
  for (int idx = tid; idx < 64 * NCLS / 4; idx += 256) dst[idx] = src[idx];
  __syncthreads();

  int a = tid >> 2, s = tid & 3;
  const float* row = st + a * NCLS;
  int c0 = s * 20;
  int cnt = (s == 3) ? 21 : 20;
  u64 key = 0;
  for (int k = 0; k < cnt; ++k) {
    int c = c0 + k;
    u64 k2 = ((u64)__float_as_uint(row[c]) << 7) | (u32)(127 - c);
    if (k2 > key) key = k2;
  }
  u64 o = __shfl_xor(key, 1); if (o > key) key = o;
  o = __shfl_xor(key, 2); if (o > key) key = o;
  if (s == 0) {
    float v = __uint_as_float((u32)(key >> 7));
    int c = 127 - (int)(key & 127);
    int n = (blockIdx.x * 64 + a) & (NANCH - 1);
    bool valid = (v > SCORE_TH) && (c != 0);
    float sc = valid ? v : -1.0f;
    outk[a] = ((u64)f2sort(sc) << 32) | (u64)(0xFFFFFFFFu - (u32)n);
    outc[a] = (u8)c;
  }
  __syncthreads();
  if (tid < 64) {
    int g = blockIdx.x * 64 + tid;
    u64 k = outk[tid];
    keys[g] = k;
    keyhi[g] = (u32)(k >> 32);
    cats[g] = outc[tid];
  }
}

// -------- wave-scan digit finder: 2 barriers, wave 0 does the scan ---------
template <int B>
__device__ void scan_digit_fast(const u32* gh, int need, u32* sbuf,
                                int tid, int* D, int* NO) {
  const int CS = B / 256;
  if (tid < 256) {
    int hi = B - 1 - tid * CS;
    u32 s = 0;
    #pragma unroll 4
    for (int k = 0; k < CS; ++k) s += gh[hi - k];
    sbuf[tid] = s;
  }
  __syncthreads();
  if (tid < 64) {
    u32 v0 = sbuf[tid * 4], v1 = sbuf[tid * 4 + 1];
    u32 v2 = sbuf[tid * 4 + 2], v3 = sbuf[tid * 4 + 3];
    u32 loc = v0 + v1 + v2 + v3;
    u32 inc = loc;
    #pragma unroll
    for (int off = 1; off < 64; off <<= 1) {
      u32 ov = __shfl_up(inc, off);
      if (tid >= off) inc += ov;
    }
    u32 exc = inc - loc;
    if (exc < (u32)need && inc >= (u32)need) {  // unique lane
      int acc = (int)exc;
      u32 vs[4] = {v0, v1, v2, v3};
      #pragma unroll
      for (int c = 0; c < 4; ++c) {
        if (acc + (int)vs[c] >= need) {
          int h2 = B - 1 - (tid * 4 + c) * CS;
          for (int k = 0; k < CS; ++k) {
            u32 h = gh[h2 - k];
            acc += (int)h;
            if (acc >= need) {
              sbuf[256] = (u32)(h2 - k);
              sbuf[257] = (u32)(need - (acc - (int)h));
              break;
            }
          }
          break;
        }
        acc += (int)vs[c];
      }
    }
  }
  __syncthreads();
  *D = (int)sbuf[256];
  *NO = (int)sbuf[257];
  __syncthreads();
}

// ---------------- kernel 2: fused select+compact+rank+emit, 1 WG/batch -----
// pass 1: warp-aggregated (<=4 distinct top-byte digits by construction);
// passes 2/3: plain LDS atomics (digits diverse -> few conflicts).
__global__ __launch_bounds__(1024) void k_sel(const u64* __restrict__ keys,
                                              const u32* __restrict__ keyhi,
                                              const u8* __restrict__ cats,
                                              const float* __restrict__ boxes,
                                              float4* __restrict__ candOff,
                                              float4* __restrict__ candOrig,
                                              float* __restrict__ candScore,
                                              int* __restrict__ candCat) {
  int b = blockIdx.x;
  int tid = threadIdx.x;
  int lane = tid & 63;
  __shared__ u32 hist[4096];   // 16 KB
  __shared__ u32 sbuf[258];
  __shared__ u64 selk[PRE_K];  // 16 KB
  __shared__ u64 ties[128];
  __shared__ u32 s_cnt, s_tcnt;

  const u64* bk = keys + (size_t)b * NANCH;
  const u32* bh = keyhi + (size_t)b * NANCH;

  if (tid == 0) { s_cnt = 0; s_tcnt = 0; }
  for (int i = tid; i < 4096; i += 1024) hist[i] = 0;
  __syncthreads();

  // ---- pass 1: top 8 bits, warp-aggregated (<=4 distinct digits)
  for (int i = tid; i < NANCH; i += 1024) {
    u32 d = bh[i] >> 24;
    u64 todo = ~0ull;
    while (todo) {
      int src = __ffsll((unsigned long long)todo) - 1;
      u32 dd = __shfl(d, src);
      u64 match = __ballot(d == dd);
      if (lane == src) atomicAdd(&hist[dd], (u32)__popcll(match));
      todo &= ~match;
    }
  }
  __syncthreads();
  int D1, n1;
  scan_digit_fast<256>(hist, PRE_K, sbuf, tid, &D1, &n1);

  for (int i = tid; i < 4096; i += 1024) hist[i] = 0;
  __syncthreads();

  // ---- pass 2: next 12 bits, plain atomics (mantissa bits -> diverse)
  u32 p1 = (u32)D1;
  for (int i = tid; i < NANCH; i += 1024) {
    u32 h = bh[i];
    if ((h >> 24) == p1) atomicAdd(&hist[(h >> 12) & 0xFFF], 1u);
  }
  __syncthreads();
  int D2, n2;
  scan_digit_fast<4096>(hist, n1, sbuf, tid, &D2, &n2);

  for (int i = tid; i < 4096; i += 1024) hist[i] = 0;
  __syncthreads();

  // ---- pass 3: low 12 bits, plain atomics
  u32 p2 = (p1 << 12) | (u32)D2;
  for (int i = tid; i < NANCH; i += 1024) {
    u32 h = bh[i];
    if ((h >> 12) == p2) atomicAdd(&hist[h & 0xFFF], 1u);
  }
  __syncthreads();
  int D3, n3;
  scan_digit_fast<4096>(hist, n2, sbuf, tid, &D3, &n3);

  u32 S32 = (p2 << 12) | (u32)D3;
  int need3 = n3;

  // ---- compaction into LDS (wave-aggregated counter)
  for (int i = tid; i < NANCH; i += 1024) {
    u64 k = bk[i];
    u32 k32 = (u32)(k >> 32);
    bool gt = k32 > S32;
    u64 m = __ballot(gt);
    u32 wbase = 0;
    if (lane == 0 && m) wbase = atomicAdd(&s_cnt, (u32)__popcll(m));
    wbase = __shfl(wbase, 0);
    if (gt) {
      u32 pos = wbase + (u32)__popcll(m & ((1ull << lane) - 1));
      if (pos < PRE_K) selk[pos] = k;
    }
    if (k32 == S32) {
      u32 tp = atomicAdd(&s_tcnt, 1u);
      if (tp < 128) ties[tp] = k;
    }
  }
  __syncthreads();

  // ---- boundary-tie resolve
  int nt = (int)s_tcnt; if (nt > 128) nt = 128;
  int base = (int)s_cnt;  // == PRE_K - need3
  if (tid < nt) {
    u64 my = ties[tid];
    int r = 0;
    for (int j = 0; j < nt; ++j) r += (ties[j] > my);
    if (r < need3 && base + r < PRE_K) selk[base + r] = my;
  }
  __syncthreads();

  // ---- rank-by-count + gather + emit (2 candidates per thread)
  for (int idx = tid; idx < PRE_K; idx += 1024) {
    u64 my = selk[idx];
    int rank = 0;
    #pragma unroll 8
    for (int j = 0; j < PRE_K; ++j) rank += (selk[j] > my);
    u32 n = 0xFFFFFFFFu - (u32)(my & 0xFFFFFFFFu);
    float s = sort2f((u32)(my >> 32));
    int cat = (int)cats[(size_t)b * NANCH + n];
    const float* bp = boxes + ((size_t)b * NANCH + n) * 4;
    float4 ob = make_float4(bp[0], bp[1], bp[2], bp[3]);
    float off = 2.0f * (float)cat;
    float4 obo = make_float4(ob.x + off, ob.y + off, ob.z + off, ob.w + off);
    int o = b * PRE_K + rank;
    candOff[o] = obo;
    candOrig[o] = ob;
    candScore[o] = s;
    candCat[o] = cat;
  }
}

// ---------------- 2048x2048 upper-triangle suppression bitmask -------------
__global__ __launch_bounds__(256) void k_mask(const float4* __restrict__ candOff,
                                              u64* __restrict__ mask) {
  int b = blockIdx.y;
  int tid = threadIdx.x;
  int wave = tid >> 6, lane = tid & 63;
  __shared__ float4 sb[PRE_K];   // 32 KB
  __shared__ float sarea[PRE_K]; // 8 KB
  for (int j = tid; j < PRE_K; j += 256) {
    float4 v = candOff[b * PRE_K + j];
    sb[j] = v;
    sarea[j] = fmaxf(v.z - v.x, 0.0f) * fmaxf(v.w - v.y, 0.0f);
  }
  __syncthreads();

  int gw = blockIdx.x * 4 + wave;
  for (int k = 0; k < PRE_K / 256; ++k) {
    int i = gw + 256 * k;
    float4 bi = sb[i];
    float ai = sarea[i];
    int c0 = i >> 6;
    u64 myword = 0;
    for (int c = c0; c < 32; ++c) {
      float4 bj = sb[c * 64 + lane];
      float aj = sarea[c * 64 + lane];
      float lx = fmaxf(bi.x, bj.x), ly = fmaxf(bi.y, bj.y);
      float rx = fminf(bi.z, bj.z), ry = fminf(bi.w, bj.w);
      float iw = fmaxf(rx - lx, 0.0f), ih = fmaxf(ry - ly, 0.0f);
      float inter = iw * ih;
      float uni = fmaxf(ai + aj - inter, 1e-9f);
      u64 word = __ballot(inter > 0.5f * uni);
      if (lane == c) myword = word;
    }
    if (lane < 32) mask[((size_t)(b * PRE_K + i)) * 32 + lane] = myword;
  }
}

// ---------------- greedy scan + output (8-deep row prefetch) ---------------
__global__ __launch_bounds__(64) void k_scan(const u64* __restrict__ mask,
                                             const float4* __restrict__ candOrig,
                                             const float* __restrict__ candScore,
                                             const int* __restrict__ candCat,
                                             float* __restrict__ out) {
  int b = blockIdx.x;
  int tid = threadIdx.x;
  __shared__ float ssc[PRE_K];
  __shared__ int keptI[MAX_OUT];
  for (int j = tid; j < PRE_K; j += 64) ssc[j] = candScore[b * PRE_K + j];
  __syncthreads();

  const u64* mrow = mask + (size_t)b * PRE_K * 32;
  int wsel = tid & 31;
  bool lo32 = tid < 32;
  u64 remv = 0;
  int cnt = 0;

  u64 c0=0,c1=0,c2=0,c3=0,c4=0,c5=0,c6=0,c7=0;
  if (lo32) {
    c0 = mrow[0 * 32 + wsel]; c1 = mrow[1 * 32 + wsel];
    c2 = mrow[2 * 32 + wsel]; c3 = mrow[3 * 32 + wsel];
    c4 = mrow[4 * 32 + wsel]; c5 = mrow[5 * 32 + wsel];
    c6 = mrow[6 * 32 + wsel]; c7 = mrow[7 * 32 + wsel];
  }

#define PROCESS(I, RK)                                   \
  {                                                      \
    u64 wb = __shfl(remv, (I) >> 6);                     \
    bool sup = (wb >> ((I) & 63)) & 1ull;                \
    if (!sup && ssc[I] > SCORE_TH) {                     \
      if (tid == 0 && cnt < MAX_OUT) keptI[cnt] = (I);   \
      if (lo32) remv |= (RK);                            \
      cnt++;                                             \
    }                                                    \
  }

  for (int base = 0; base < PRE_K; base += 8) {
    u64 n0=0,n1=0,n2=0,n3=0,n4=0,n5=0,n6=0,n7=0;
    if (base + 8 < PRE_K && lo32) {
      const u64* nr = mrow + (size_t)(base + 8) * 32 + wsel;
      n0 = nr[0 * 32]; n1 = nr[1 * 32]; n2 = nr[2 * 32]; n3 = nr[3 * 32];
      n4 = nr[4 * 32]; n5 = nr[5 * 32]; n6 = nr[6 * 32]; n7 = nr[7 * 32];
    }
    PROCESS(base + 0, c0); PROCESS(base + 1, c1);
    PROCESS(base + 2, c2); PROCESS(base + 3, c3);
    PROCESS(base + 4, c4); PROCESS(base + 5, c5);
    PROCESS(base + 6, c6); PROCESS(base + 7, c7);
    c0=n0; c1=n1; c2=n2; c3=n3; c4=n4; c5=n5; c6=n6; c7=n7;
    if (cnt >= MAX_OUT) break;
  }
#undef PROCESS

  int kc = cnt < MAX_OUT ? cnt : MAX_OUT;
  __syncthreads();

  float* out5 = out;
  float* ocat = out + BATCH * MAX_OUT * 5;
  for (int r = tid; r < MAX_OUT; r += 64) {
    float* p = out5 + ((size_t)(b * MAX_OUT + r)) * 5;
    if (r < kc) {
      int i = keptI[r];
      float4 ob = candOrig[b * PRE_K + i];
      p[0] = ob.x; p[1] = ob.y; p[2] = ob.z; p[3] = ob.w; p[4] = ssc[i];
      ocat[b * MAX_OUT + r] = (float)candCat[b * PRE_K + i];
    } else {
      p[0] = 0.0f; p[1] = 0.0f; p[2] = 0.0f; p[3] = 0.0f; p[4] = 0.0f;
      ocat[b * MAX_OUT + r] = 0.0f;
    }
  }
}

extern "C" void kernel_launch(void* const* d_in, const int* in_sizes, int n_in,
                              void* d_out, int out_size, void* d_ws, size_t ws_size,
                              hipStream_t stream) {
  const float* boxes = (const float*)d_in[0];
  const float* confs = (const float*)d_in[1];
  float* out = (float*)d_out;
  char* ws = (char*)d_ws;

  const size_t OFF_KEYS = 0;                            // 2 MB
  const size_t OFF_KHI  = (size_t)2 << 20;              // 1 MB (u32 hi words)
  const size_t OFF_CATS = OFF_KHI + (1u << 20);         // 256 KB (u8)
  const size_t OFF_COFF = OFF_CATS + (256u << 10);      // 256 KB
  const size_t OFF_CORG = OFF_COFF + (256u << 10);      // 256 KB
  const size_t OFF_CSC  = OFF_CORG + (256u << 10);      // 64 KB
  const size_t OFF_CCAT = OFF_CSC + (64u << 10);        // 64 KB
  const size_t OFF_MASK = OFF_CCAT + (64u << 10);       // 4 MB

  u64* keys    = (u64*)(ws + OFF_KEYS);
  u32* keyhi   = (u32*)(ws + OFF_KHI);
  u8* cats     = (u8*)(ws + OFF_CATS);
  float4* cOff = (float4*)(ws + OFF_COFF);
  float4* cOrg = (float4*)(ws + OFF_CORG);
  float* cSc   = (float*)(ws + OFF_CSC);
  int* cCat    = (int*)(ws + OFF_CCAT);
  u64* mask    = (u64*)(ws + OFF_MASK);

  k_score<<<BATCH * NANCH / 64, 256, 0, stream>>>(confs, keys, keyhi, cats);
  k_sel<<<BATCH, 1024, 0, stream>>>(keys, keyhi, cats, boxes, cOff, cOrg, cSc, cCat);
  dim3 g3(64, BATCH);
  k_mask<<<g3, 256, 0, stream>>>(cOff, mask);
  k_scan<<<BATCH, 64, 0, stream>>>(mask, cOrg, cSc, cCat, out);
}

// Round 9
// 150.773 us; speedup vs baseline: 2.4512x; 1.3148x over previous
//
#include <hip/hip_runtime.h>
#include <stdint.h>

#define BATCH 8
#define NANCH 32768
#define NCLS 81
#define PRE_K 2048
#define MAX_OUT 200
#define IOU_TH 0.5f
#define SCORE_TH 0.05f

typedef uint32_t u32;
typedef uint64_t u64;
typedef uint8_t u8;

// monotone float->u32 (order-preserving)
__device__ __forceinline__ u32 f2sort(float f) {
  u32 u = __float_as_uint(f);
  return (u & 0x80000000u) ? ~u : (u | 0x80000000u);
}
__device__ __forceinline__ float sort2f(u32 u) {
  u = (u & 0x80000000u) ? (u & 0x7FFFFFFFu) : ~u;
  return __uint_as_float(u);
}

// ---------------- kernel 1: per-anchor max/argmax over 81 classes ----------
__global__ __launch_bounds__(256) void k_score(const float* __restrict__ confs,
                                               u64* __restrict__ keys,
                                               u32* __restrict__ keyhi,
                                               u8* __restrict__ cats) {
  __shared__ float st[64 * NCLS];  // 20.25 KB
  __shared__ u64 outk[64];
  __shared__ u8 outc[64];
  int tid = threadIdx.x;
  const float4* src = (const float4*)confs + (size_t)blockIdx.x * (64 * NCLS / 4);
  float4* dst = (float4*)st;
  for (int idx = tid; idx < 64 * NCLS / 4; idx += 256) dst[idx] = src[idx];
  __syncthreads();

  int a = tid >> 2, s = tid & 3;
  const float* row = st + a * NCLS;
  int c0 = s * 20;
  int cnt = (s == 3) ? 21 : 20;
  u64 key = 0;
  for (int k = 0; k < cnt; ++k) {
    int c = c0 + k;
    u64 k2 = ((u64)__float_as_uint(row[c]) << 7) | (u32)(127 - c);
    if (k2 > key) key = k2;
  }
  u64 o = __shfl_xor(key, 1); if (o > key) key = o;
  o = __shfl_xor(key, 2); if (o > key) key = o;
  if (s == 0) {
    float v = __uint_as_float((u32)(key >> 7));
    int c = 127 - (int)(key & 127);
    int n = (blockIdx.x * 64 + a) & (NANCH - 1);
    bool valid = (v > SCORE_TH) && (c != 0);
    float sc = valid ? v : -1.0f;
    outk[a] = ((u64)f2sort(sc) << 32) | (u64)(0xFFFFFFFFu - (u32)n);
    outc[a] = (u8)c;
  }
  __syncthreads();
  if (tid < 64) {
    int g = blockIdx.x * 64 + tid;
    u64 k = outk[tid];
    keys[g] = k;
    keyhi[g] = (u32)(k >> 32);
    cats[g] = outc[tid];
  }
}

// -------- wave-scan digit finder: 2 barriers, wave 0 does the scan ---------
template <int B>
__device__ void scan_digit_fast(const u32* gh, int need, u32* sbuf,
                                int tid, int* D, int* NO) {
  const int CS = B / 256;
  if (tid < 256) {
    int hi = B - 1 - tid * CS;
    u32 s = 0;
    #pragma unroll 4
    for (int k = 0; k < CS; ++k) s += gh[hi - k];
    sbuf[tid] = s;
  }
  __syncthreads();
  if (tid < 64) {
    u32 v0 = sbuf[tid * 4], v1 = sbuf[tid * 4 + 1];
    u32 v2 = sbuf[tid * 4 + 2], v3 = sbuf[tid * 4 + 3];
    u32 loc = v0 + v1 + v2 + v3;
    u32 inc = loc;
    #pragma unroll
    for (int off = 1; off < 64; off <<= 1) {
      u32 ov = __shfl_up(inc, off);
      if (tid >= off) inc += ov;
    }
    u32 exc = inc - loc;
    if (exc < (u32)need && inc >= (u32)need) {  // unique lane
      int acc = (int)exc;
      u32 vs[4] = {v0, v1, v2, v3};
      #pragma unroll
      for (int c = 0; c < 4; ++c) {
        if (acc + (int)vs[c] >= need) {
          int h2 = B - 1 - (tid * 4 + c) * CS;
          for (int k = 0; k < CS; ++k) {
            u32 h = gh[h2 - k];
            acc += (int)h;
            if (acc >= need) {
              sbuf[256] = (u32)(h2 - k);
              sbuf[257] = (u32)(need - (acc - (int)h));
              break;
            }
          }
          break;
        }
        acc += (int)vs[c];
      }
    }
  }
  __syncthreads();
  *D = (int)sbuf[256];
  *NO = (int)sbuf[257];
  __syncthreads();
}

// ---------------- kernel 2: fused select+compact+sort+emit, 1 WG/batch -----
// pass 1 warp-aggregated; passes 2/3 plain LDS atomics; order via bitonic
// sort (per-lane LDS access, ~15x fewer LDS instrs than broadcast rank).
__global__ __launch_bounds__(1024) void k_sel(const u64* __restrict__ keys,
                                              const u32* __restrict__ keyhi,
                                              const u8* __restrict__ cats,
                                              const float* __restrict__ boxes,
                                              float4* __restrict__ candOff,
                                              float4* __restrict__ candOrig,
                                              float* __restrict__ candScore,
                                              int* __restrict__ candCat) {
  int b = blockIdx.x;
  int tid = threadIdx.x;
  int lane = tid & 63;
  __shared__ u32 hist[4096];   // 16 KB
  __shared__ u32 sbuf[258];
  __shared__ u64 selk[PRE_K];  // 16 KB
  __shared__ u64 ties[128];
  __shared__ u32 s_cnt, s_tcnt;

  const u64* bk = keys + (size_t)b * NANCH;
  const u32* bh = keyhi + (size_t)b * NANCH;

  if (tid == 0) { s_cnt = 0; s_tcnt = 0; }
  for (int i = tid; i < 4096; i += 1024) hist[i] = 0;
  __syncthreads();

  // ---- pass 1: top 8 bits, warp-aggregated (<=4 distinct digits)
  for (int i = tid; i < NANCH; i += 1024) {
    u32 d = bh[i] >> 24;
    u64 todo = ~0ull;
    while (todo) {
      int src = __ffsll((unsigned long long)todo) - 1;
      u32 dd = __shfl(d, src);
      u64 match = __ballot(d == dd);
      if (lane == src) atomicAdd(&hist[dd], (u32)__popcll(match));
      todo &= ~match;
    }
  }
  __syncthreads();
  int D1, n1;
  scan_digit_fast<256>(hist, PRE_K, sbuf, tid, &D1, &n1);

  for (int i = tid; i < 4096; i += 1024) hist[i] = 0;
  __syncthreads();

  // ---- pass 2: next 12 bits, plain atomics (mantissa bits -> diverse)
  u32 p1 = (u32)D1;
  for (int i = tid; i < NANCH; i += 1024) {
    u32 h = bh[i];
    if ((h >> 24) == p1) atomicAdd(&hist[(h >> 12) & 0xFFF], 1u);
  }
  __syncthreads();
  int D2, n2;
  scan_digit_fast<4096>(hist, n1, sbuf, tid, &D2, &n2);

  for (int i = tid; i < 4096; i += 1024) hist[i] = 0;
  __syncthreads();

  // ---- pass 3: low 12 bits, plain atomics
  u32 p2 = (p1 << 12) | (u32)D2;
  for (int i = tid; i < NANCH; i += 1024) {
    u32 h = bh[i];
    if ((h >> 12) == p2) atomicAdd(&hist[h & 0xFFF], 1u);
  }
  __syncthreads();
  int D3, n3;
  scan_digit_fast<4096>(hist, n2, sbuf, tid, &D3, &n3);

  u32 S32 = (p2 << 12) | (u32)D3;
  int need3 = n3;

  // ---- compaction into LDS (wave-aggregated counter)
  for (int i = tid; i < NANCH; i += 1024) {
    u64 k = bk[i];
    u32 k32 = (u32)(k >> 32);
    bool gt = k32 > S32;
    u64 m = __ballot(gt);
    u32 wbase = 0;
    if (lane == 0 && m) wbase = atomicAdd(&s_cnt, (u32)__popcll(m));
    wbase = __shfl(wbase, 0);
    if (gt) {
      u32 pos = wbase + (u32)__popcll(m & ((1ull << lane) - 1));
      if (pos < PRE_K) selk[pos] = k;
    }
    if (k32 == S32) {
      u32 tp = atomicAdd(&s_tcnt, 1u);
      if (tp < 128) ties[tp] = k;
    }
  }
  __syncthreads();

  // ---- boundary-tie resolve
  int nt = (int)s_tcnt; if (nt > 128) nt = 128;
  int base = (int)s_cnt;  // == PRE_K - need3
  if (tid < nt) {
    u64 my = ties[tid];
    int r = 0;
    for (int j = 0; j < nt; ++j) r += (ties[j] > my);
    if (r < need3 && base + r < PRE_K) selk[base + r] = my;
  }
  __syncthreads();

  // ---- bitonic sort ascending over 2048 distinct keys (verified in R1)
  for (int k = 2; k <= PRE_K; k <<= 1) {
    for (int j = k >> 1; j > 0; j >>= 1) {
      for (int idx = tid; idx < PRE_K; idx += 1024) {
        int ixj = idx ^ j;
        if (ixj > idx) {
          u64 a = selk[idx], c = selk[ixj];
          bool up = ((idx & k) == 0);
          if ((a > c) == up) { selk[idx] = c; selk[ixj] = a; }
        }
      }
      __syncthreads();
    }
  }

  // ---- emit rank-ordered candidates (rank r = skeys[PRE_K-1-r])
  for (int r = tid; r < PRE_K; r += 1024) {
    u64 my = selk[PRE_K - 1 - r];
    u32 n = 0xFFFFFFFFu - (u32)(my & 0xFFFFFFFFu);
    float s = sort2f((u32)(my >> 32));
    int cat = (int)cats[(size_t)b * NANCH + n];
    const float* bp = boxes + ((size_t)b * NANCH + n) * 4;
    float4 ob = make_float4(bp[0], bp[1], bp[2], bp[3]);
    float off = 2.0f * (float)cat;
    float4 obo = make_float4(ob.x + off, ob.y + off, ob.z + off, ob.w + off);
    int o = b * PRE_K + r;
    candOff[o] = obo;
    candOrig[o] = ob;
    candScore[o] = s;
    candCat[o] = cat;
  }
}

// ---------------- 2048x2048 upper-triangle suppression bitmask -------------
__global__ __launch_bounds__(256) void k_mask(const float4* __restrict__ candOff,
                                              u64* __restrict__ mask) {
  int b = blockIdx.y;
  int tid = threadIdx.x;
  int wave = tid >> 6, lane = tid & 63;
  __shared__ float4 sb[PRE_K];   // 32 KB
  __shared__ float sarea[PRE_K]; // 8 KB
  for (int j = tid; j < PRE_K; j += 256) {
    float4 v = candOff[b * PRE_K + j];
    sb[j] = v;
    sarea[j] = fmaxf(v.z - v.x, 0.0f) * fmaxf(v.w - v.y, 0.0f);
  }
  __syncthreads();

  int gw = blockIdx.x * 4 + wave;
  for (int k = 0; k < PRE_K / 256; ++k) {
    int i = gw + 256 * k;
    float4 bi = sb[i];
    float ai = sarea[i];
    int c0 = i >> 6;
    u64 myword = 0;
    for (int c = c0; c < 32; ++c) {
      float4 bj = sb[c * 64 + lane];
      float aj = sarea[c * 64 + lane];
      float lx = fmaxf(bi.x, bj.x), ly = fmaxf(bi.y, bj.y);
      float rx = fminf(bi.z, bj.z), ry = fminf(bi.w, bj.w);
      float iw = fmaxf(rx - lx, 0.0f), ih = fmaxf(ry - ly, 0.0f);
      float inter = iw * ih;
      float uni = fmaxf(ai + aj - inter, 1e-9f);
      u64 word = __ballot(inter > 0.5f * uni);
      if (lane == c) myword = word;
    }
    if (lane < 32) mask[((size_t)(b * PRE_K + i)) * 32 + lane] = myword;
  }
}

// ---------------- greedy scan + output (8-deep row prefetch) ---------------
__global__ __launch_bounds__(64) void k_scan(const u64* __restrict__ mask,
                                             const float4* __restrict__ candOrig,
                                             const float* __restrict__ candScore,
                                             const int* __restrict__ candCat,
                                             float* __restrict__ out) {
  int b = blockIdx.x;
  int tid = threadIdx.x;
  __shared__ float ssc[PRE_K];
  __shared__ int keptI[MAX_OUT];
  for (int j = tid; j < PRE_K; j += 64) ssc[j] = candScore[b * PRE_K + j];
  __syncthreads();

  const u64* mrow = mask + (size_t)b * PRE_K * 32;
  int wsel = tid & 31;
  bool lo32 = tid < 32;
  u64 remv = 0;
  int cnt = 0;

  u64 c0=0,c1=0,c2=0,c3=0,c4=0,c5=0,c6=0,c7=0;
  if (lo32) {
    c0 = mrow[0 * 32 + wsel]; c1 = mrow[1 * 32 + wsel];
    c2 = mrow[2 * 32 + wsel]; c3 = mrow[3 * 32 + wsel];
    c4 = mrow[4 * 32 + wsel]; c5 = mrow[5 * 32 + wsel];
    c6 = mrow[6 * 32 + wsel]; c7 = mrow[7 * 32 + wsel];
  }

#define PROCESS(I, RK)                                   \
  {                                                      \
    u64 wb = __shfl(remv, (I) >> 6);                     \
    bool sup = (wb >> ((I) & 63)) & 1ull;                \
    if (!sup && ssc[I] > SCORE_TH) {                     \
      if (tid == 0 && cnt < MAX_OUT) keptI[cnt] = (I);   \
      if (lo32) remv |= (RK);                            \
      cnt++;                                             \
    }                                                    \
  }

  for (int base = 0; base < PRE_K; base += 8) {
    u64 n0=0,n1=0,n2=0,n3=0,n4=0,n5=0,n6=0,n7=0;
    if (base + 8 < PRE_K && lo32) {
      const u64* nr = mrow + (size_t)(base + 8) * 32 + wsel;
      n0 = nr[0 * 32]; n1 = nr[1 * 32]; n2 = nr[2 * 32]; n3 = nr[3 * 32];
      n4 = nr[4 * 32]; n5 = nr[5 * 32]; n6 = nr[6 * 32]; n7 = nr[7 * 32];
    }
    PROCESS(base + 0, c0); PROCESS(base + 1, c1);
    PROCESS(base + 2, c2); PROCESS(base + 3, c3);
    PROCESS(base + 4, c4); PROCESS(base + 5, c5);
    PROCESS(base + 6, c6); PROCESS(base + 7, c7);
    c0=n0; c1=n1; c2=n2; c3=n3; c4=n4; c5=n5; c6=n6; c7=n7;
    if (cnt >= MAX_OUT) break;
  }
#undef PROCESS

  int kc = cnt < MAX_OUT ? cnt : MAX_OUT;
  __syncthreads();

  float* out5 = out;
  float* ocat = out + BATCH * MAX_OUT * 5;
  for (int r = tid; r < MAX_OUT; r += 64) {
    float* p = out5 + ((size_t)(b * MAX_OUT + r)) * 5;
    if (r < kc) {
      int i = keptI[r];
      float4 ob = candOrig[b * PRE_K + i];
      p[0] = ob.x; p[1] = ob.y; p[2] = ob.z; p[3] = ob.w; p[4] = ssc[i];
      ocat[b * MAX_OUT + r] = (float)candCat[b * PRE_K + i];
    } else {
      p[0] = 0.0f; p[1] = 0.0f; p[2] = 0.0f; p[3] = 0.0f; p[4] = 0.0f;
      ocat[b * MAX_OUT + r] = 0.0f;
    }
  }
}

extern "C" void kernel_launch(void* const* d_in, const int* in_sizes, int n_in,
                              void* d_out, int out_size, void* d_ws, size_t ws_size,
                              hipStream_t stream) {
  const float* boxes = (const float*)d_in[0];
  const float* confs = (const float*)d_in[1];
  float* out = (float*)d_out;
  char* ws = (char*)d_ws;

  const size_t OFF_KEYS = 0;                            // 2 MB
  const size_t OFF_KHI  = (size_t)2 << 20;              // 1 MB (u32 hi words)
  const size_t OFF_CATS = OFF_KHI + (1u << 20);         // 256 KB (u8)
  const size_t OFF_COFF = OFF_CATS + (256u << 10);      // 256 KB
  const size_t OFF_CORG = OFF_COFF + (256u << 10);      // 256 KB
  const size_t OFF_CSC  = OFF_CORG + (256u << 10);      // 64 KB
  const size_t OFF_CCAT = OFF_CSC + (64u << 10);        // 64 KB
  const size_t OFF_MASK = OFF_CCAT + (64u << 10);       // 4 MB

  u64* keys    = (u64*)(ws + OFF_KEYS);
  u32* keyhi   = (u32*)(ws + OFF_KHI);
  u8* cats     = (u8*)(ws + OFF_CATS);
  float4* cOff = (float4*)(ws + OFF_COFF);
  float4* cOrg = (float4*)(ws + OFF_CORG);
  float* cSc   = (float*)(ws + OFF_CSC);
  int* cCat    = (int*)(ws + OFF_CCAT);
  u64* mask    = (u64*)(ws + OFF_MASK);

  k_score<<<BATCH * NANCH / 64, 256, 0, stream>>>(confs, keys, keyhi, cats);
  k_sel<<<BATCH, 1024, 0, stream>>>(keys, keyhi, cats, boxes, cOff, cOrg, cSc, cCat);
  dim3 g3(64, BATCH);
  k_mask<<<g3, 256, 0, stream>>>(cOff, mask);
  k_scan<<<BATCH, 64, 0, stream>>>(mask, cOrg, cSc, cCat, out);
}

// Round 10
// 127.443 us; speedup vs baseline: 2.9000x; 1.1831x over previous
//
#include <hip/hip_runtime.h>
#include <stdint.h>

#define BATCH 8
#define NANCH 32768
#define NCLS 81
#define PRE_K 2048
#define MAX_OUT 200
#define IOU_TH 0.5f
#define SCORE_TH 0.05f

typedef uint32_t u32;
typedef uint64_t u64;
typedef uint8_t u8;

// monotone float->u32 (order-preserving)
__device__ __forceinline__ u32 f2sort(float f) {
  u32 u = __float_as_uint(f);
  return (u & 0x80000000u) ? ~u : (u | 0x80000000u);
}
__device__ __forceinline__ float sort2f(u32 u) {
  u = (u & 0x80000000u) ? (u & 0x7FFFFFFFu) : ~u;
  return __uint_as_float(u);
}

// ---------------- kernel 1: per-anchor max/argmax over 81 classes ----------
__global__ __launch_bounds__(256) void k_score(const float* __restrict__ confs,
                                               u32* __restrict__ keyhi,
                                               u8* __restrict__ cats) {
  __shared__ float st[64 * NCLS];  // 20.25 KB
  __shared__ u32 outh[64];
  __shared__ u8 outc[64];
  int tid = threadIdx.x;
  const float4* src = (const float4*)confs + (size_t)blockIdx.x * (64 * NCLS / 4);
  float4* dst = (float4*)st;
  for (int idx = tid; idx < 64 * NCLS / 4; idx += 256) dst[idx] = src[idx];
  __syncthreads();

  int a = tid >> 2, s = tid & 3;
  const float* row = st + a * NCLS;
  int c0 = s * 20;
  int cnt = (s == 3) ? 21 : 20;
  u64 key = 0;
  for (int k = 0; k < cnt; ++k) {
    int c = c0 + k;
    u64 k2 = ((u64)__float_as_uint(row[c]) << 7) | (u32)(127 - c);
    if (k2 > key) key = k2;
  }
  u64 o = __shfl_xor(key, 1); if (o > key) key = o;
  o = __shfl_xor(key, 2); if (o > key) key = o;
  if (s == 0) {
    float v = __uint_as_float((u32)(key >> 7));
    int c = 127 - (int)(key & 127);
    bool valid = (v > SCORE_TH) && (c != 0);
    float sc = valid ? v : -1.0f;
    outh[a] = f2sort(sc);
    outc[a] = (u8)c;
  }
  __syncthreads();
  if (tid < 64) {
    int g = blockIdx.x * 64 + tid;
    keyhi[g] = outh[tid];
    cats[g] = outc[tid];
  }
}

// -------- wave-scan digit finder: 2 barriers, wave 0 does the scan ---------
template <int B>
__device__ void scan_digit_fast(const u32* gh, int need, u32* sbuf,
                                int tid, int* D, int* NO) {
  const int CS = B / 256;
  if (tid < 256) {
    int hi = B - 1 - tid * CS;
    u32 s = 0;
    #pragma unroll 4
    for (int k = 0; k < CS; ++k) s += gh[hi - k];
    sbuf[tid] = s;
  }
  __syncthreads();
  if (tid < 64) {
    u32 v0 = sbuf[tid * 4], v1 = sbuf[tid * 4 + 1];
    u32 v2 = sbuf[tid * 4 + 2], v3 = sbuf[tid * 4 + 3];
    u32 loc = v0 + v1 + v2 + v3;
    u32 inc = loc;
    #pragma unroll
    for (int off = 1; off < 64; off <<= 1) {
      u32 ov = __shfl_up(inc, off);
      if (tid >= off) inc += ov;
    }
    u32 exc = inc - loc;
    if (exc < (u32)need && inc >= (u32)need) {  // unique lane
      int acc = (int)exc;
      u32 vs[4] = {v0, v1, v2, v3};
      #pragma unroll
      for (int c = 0; c < 4; ++c) {
        if (acc + (int)vs[c] >= need) {
          int h2 = B - 1 - (tid * 4 + c) * CS;
          for (int k = 0; k < CS; ++k) {
            u32 h = gh[h2 - k];
            acc += (int)h;
            if (acc >= need) {
              sbuf[256] = (u32)(h2 - k);
              sbuf[257] = (u32)(need - (acc - (int)h));
              break;
            }
          }
          break;
        }
        acc += (int)vs[c];
      }
    }
  }
  __syncthreads();
  *D = (int)sbuf[256];
  *NO = (int)sbuf[257];
  __syncthreads();
}

// ---------------- kernel 2: fused select+compact+sort+emit, 1 WG/batch -----
// Thread's 32 keyhi values live in 8 uint4 registers (FULL unroll => static
// indexing, no scratch). Full u64 key reconstructed as (hi<<32)|(~n) -- the
// u64 keys array no longer exists. Pass 1 warp-aggregated; passes 2/3 plain
// LDS atomics; order via bitonic sort.
__global__ __launch_bounds__(1024) void k_sel(const u32* __restrict__ keyhi,
                                              const u8* __restrict__ cats,
                                              const float* __restrict__ boxes,
                                              float4* __restrict__ candOff,
                                              float4* __restrict__ candOrig,
                                              float* __restrict__ candScore,
                                              int* __restrict__ candCat) {
  int b = blockIdx.x;
  int tid = threadIdx.x;
  int lane = tid & 63;
  __shared__ u32 hist[4096];   // 16 KB
  __shared__ u32 sbuf[258];
  __shared__ u64 selk[PRE_K];  // 16 KB
  __shared__ u64 ties[128];
  __shared__ u32 s_cnt, s_tcnt;

  const uint4* bh4 = (const uint4*)(keyhi + (size_t)b * NANCH);

  // one round-trip: 8 coalesced 16B loads; element n = 4*tid + 4096*j + c
  uint4 hk[8];
  #pragma unroll
  for (int j = 0; j < 8; ++j) hk[j] = bh4[tid + j * 1024];

  if (tid == 0) { s_cnt = 0; s_tcnt = 0; }
  for (int i = tid; i < 4096; i += 1024) hist[i] = 0;
  __syncthreads();

#define ELEM(j, c) ((c) == 0 ? hk[j].x : (c) == 1 ? hk[j].y : (c) == 2 ? hk[j].z : hk[j].w)

  // ---- pass 1: top 8 bits, warp-aggregated (<=5 distinct digits)
  #pragma unroll
  for (int j = 0; j < 8; ++j) {
    #pragma unroll
    for (int c = 0; c < 4; ++c) {
      u32 d = ELEM(j, c) >> 24;
      u64 todo = ~0ull;
      while (todo) {
        int src = __ffsll((unsigned long long)todo) - 1;
        u32 dd = __shfl(d, src);
        u64 match = __ballot(d == dd);
        if (lane == src) atomicAdd(&hist[dd], (u32)__popcll(match));
        todo &= ~match;
      }
    }
  }
  __syncthreads();
  int D1, n1;
  scan_digit_fast<256>(hist, PRE_K, sbuf, tid, &D1, &n1);

  for (int i = tid; i < 4096; i += 1024) hist[i] = 0;
  __syncthreads();

  // ---- pass 2: next 12 bits, plain atomics (mantissa bits -> diverse)
  u32 p1 = (u32)D1;
  #pragma unroll
  for (int j = 0; j < 8; ++j) {
    #pragma unroll
    for (int c = 0; c < 4; ++c) {
      u32 h = ELEM(j, c);
      if ((h >> 24) == p1) atomicAdd(&hist[(h >> 12) & 0xFFF], 1u);
    }
  }
  __syncthreads();
  int D2, n2;
  scan_digit_fast<4096>(hist, n1, sbuf, tid, &D2, &n2);

  for (int i = tid; i < 4096; i += 1024) hist[i] = 0;
  __syncthreads();

  // ---- pass 3: low 12 bits, plain atomics
  u32 p2 = (p1 << 12) | (u32)D2;
  #pragma unroll
  for (int j = 0; j < 8; ++j) {
    #pragma unroll
    for (int c = 0; c < 4; ++c) {
      u32 h = ELEM(j, c);
      if ((h >> 12) == p2) atomicAdd(&hist[h & 0xFFF], 1u);
    }
  }
  __syncthreads();
  int D3, n3;
  scan_digit_fast<4096>(hist, n2, sbuf, tid, &D3, &n3);

  u32 S32 = (p2 << 12) | (u32)D3;
  int need3 = n3;

  // ---- compaction from registers into LDS (wave-aggregated counter)
  #pragma unroll
  for (int j = 0; j < 8; ++j) {
    #pragma unroll
    for (int c = 0; c < 4; ++c) {
      u32 h = ELEM(j, c);
      u32 n = (u32)(4 * tid + 4096 * j + c);
      u64 k = ((u64)h << 32) | (u64)(0xFFFFFFFFu - n);
      bool gt = h > S32;
      u64 m = __ballot(gt);
      u32 wbase = 0;
      if (lane == 0 && m) wbase = atomicAdd(&s_cnt, (u32)__popcll(m));
      wbase = __shfl(wbase, 0);
      if (gt) {
        u32 pos = wbase + (u32)__popcll(m & ((1ull << lane) - 1));
        if (pos < PRE_K) selk[pos] = k;
      }
      if (h == S32) {
        u32 tp = atomicAdd(&s_tcnt, 1u);
        if (tp < 128) ties[tp] = k;
      }
    }
  }
#undef ELEM
  __syncthreads();

  // ---- boundary-tie resolve
  int nt = (int)s_tcnt; if (nt > 128) nt = 128;
  int base = (int)s_cnt;  // == PRE_K - need3
  if (tid < nt) {
    u64 my = ties[tid];
    int r = 0;
    for (int j = 0; j < nt; ++j) r += (ties[j] > my);
    if (r < need3 && base + r < PRE_K) selk[base + r] = my;
  }
  __syncthreads();

  // ---- bitonic sort ascending over 2048 distinct keys
  for (int k = 2; k <= PRE_K; k <<= 1) {
    for (int j = k >> 1; j > 0; j >>= 1) {
      for (int idx = tid; idx < PRE_K; idx += 1024) {
        int ixj = idx ^ j;
        if (ixj > idx) {
          u64 a = selk[idx], c = selk[ixj];
          bool up = ((idx & k) == 0);
          if ((a > c) == up) { selk[idx] = c; selk[ixj] = a; }
        }
      }
      __syncthreads();
    }
  }

  // ---- emit rank-ordered candidates (rank r = selk[PRE_K-1-r])
  for (int r = tid; r < PRE_K; r += 1024) {
    u64 my = selk[PRE_K - 1 - r];
    u32 n = 0xFFFFFFFFu - (u32)(my & 0xFFFFFFFFu);
    float s = sort2f((u32)(my >> 32));
    int cat = (int)cats[(size_t)b * NANCH + n];
    const float* bp = boxes + ((size_t)b * NANCH + n) * 4;
    float4 ob = make_float4(bp[0], bp[1], bp[2], bp[3]);
    float off = 2.0f * (float)cat;
    float4 obo = make_float4(ob.x + off, ob.y + off, ob.z + off, ob.w + off);
    int o = b * PRE_K + r;
    candOff[o] = obo;
    candOrig[o] = ob;
    candScore[o] = s;
    candCat[o] = cat;
  }
}

// ---------------- 2048x2048 upper-triangle suppression bitmask -------------
__global__ __launch_bounds__(256) void k_mask(const float4* __restrict__ candOff,
                                              u64* __restrict__ mask) {
  int b = blockIdx.y;
  int tid = threadIdx.x;
  int wave = tid >> 6, lane = tid & 63;
  __shared__ float4 sb[PRE_K];   // 32 KB
  __shared__ float sarea[PRE_K]; // 8 KB
  for (int j = tid; j < PRE_K; j += 256) {
    float4 v = candOff[b * PRE_K + j];
    sb[j] = v;
    sarea[j] = fmaxf(v.z - v.x, 0.0f) * fmaxf(v.w - v.y, 0.0f);
  }
  __syncthreads();

  int gw = blockIdx.x * 4 + wave;
  for (int k = 0; k < PRE_K / 256; ++k) {
    int i = gw + 256 * k;
    float4 bi = sb[i];
    float ai = sarea[i];
    int c0 = i >> 6;
    u64 myword = 0;
    for (int c = c0; c < 32; ++c) {
      float4 bj = sb[c * 64 + lane];
      float aj = sarea[c * 64 + lane];
      float lx = fmaxf(bi.x, bj.x), ly = fmaxf(bi.y, bj.y);
      float rx = fminf(bi.z, bj.z), ry = fminf(bi.w, bj.w);
      float iw = fmaxf(rx - lx, 0.0f), ih = fmaxf(ry - ly, 0.0f);
      float inter = iw * ih;
      float uni = fmaxf(ai + aj - inter, 1e-9f);
      u64 word = __ballot(inter > 0.5f * uni);
      if (lane == c) myword = word;
    }
    if (lane < 32) mask[((size_t)(b * PRE_K + i)) * 32 + lane] = myword;
  }
}

// ---------------- greedy scan + output (8-deep row prefetch) ---------------
__global__ __launch_bounds__(64) void k_scan(const u64* __restrict__ mask,
                                             const float4* __restrict__ candOrig,
                                             const float* __restrict__ candScore,
                                             const int* __restrict__ candCat,
                                             float* __restrict__ out) {
  int b = blockIdx.x;
  int tid = threadIdx.x;
  __shared__ float ssc[PRE_K];
  __shared__ int keptI[MAX_OUT];
  for (int j = tid; j < PRE_K; j += 64) ssc[j] = candScore[b * PRE_K + j];
  __syncthreads();

  const u64* mrow = mask + (size_t)b * PRE_K * 32;
  int wsel = tid & 31;
  bool lo32 = tid < 32;
  u64 remv = 0;
  int cnt = 0;

  u64 c0=0,c1=0,c2=0,c3=0,c4=0,c5=0,c6=0,c7=0;
  if (lo32) {
    c0 = mrow[0 * 32 + wsel]; c1 = mrow[1 * 32 + wsel];
    c2 = mrow[2 * 32 + wsel]; c3 = mrow[3 * 32 + wsel];
    c4 = mrow[4 * 32 + wsel]; c5 = mrow[5 * 32 + wsel];
    c6 = mrow[6 * 32 + wsel]; c7 = mrow[7 * 32 + wsel];
  }

#define PROCESS(I, RK)                                   \
  {                                                      \
    u64 wb = __shfl(remv, (I) >> 6);                     \
    bool sup = (wb >> ((I) & 63)) & 1ull;                \
    if (!sup && ssc[I] > SCORE_TH) {                     \
      if (tid == 0 && cnt < MAX_OUT) keptI[cnt] = (I);   \
      if (lo32) remv |= (RK);                            \
      cnt++;                                             \
    }                                                    \
  }

  for (int base = 0; base < PRE_K; base += 8) {
    u64 n0=0,n1=0,n2=0,n3=0,n4=0,n5=0,n6=0,n7=0;
    if (base + 8 < PRE_K && lo32) {
      const u64* nr = mrow + (size_t)(base + 8) * 32 + wsel;
      n0 = nr[0 * 32]; n1 = nr[1 * 32]; n2 = nr[2 * 32]; n3 = nr[3 * 32];
      n4 = nr[4 * 32]; n5 = nr[5 * 32]; n6 = nr[6 * 32]; n7 = nr[7 * 32];
    }
    PROCESS(base + 0, c0); PROCESS(base + 1, c1);
    PROCESS(base + 2, c2); PROCESS(base + 3, c3);
    PROCESS(base + 4, c4); PROCESS(base + 5, c5);
    PROCESS(base + 6, c6); PROCESS(base + 7, c7);
    c0=n0; c1=n1; c2=n2; c3=n3; c4=n4; c5=n5; c6=n6; c7=n7;
    if (cnt >= MAX_OUT) break;
  }
#undef PROCESS

  int kc = cnt < MAX_OUT ? cnt : MAX_OUT;
  __syncthreads();

  float* out5 = out;
  float* ocat = out + BATCH * MAX_OUT * 5;
  for (int r = tid; r < MAX_OUT; r += 64) {
    float* p = out5 + ((size_t)(b * MAX_OUT + r)) * 5;
    if (r < kc) {
      int i = keptI[r];
      float4 ob = candOrig[b * PRE_K + i];
      p[0] = ob.x; p[1] = ob.y; p[2] = ob.z; p[3] = ob.w; p[4] = ssc[i];
      ocat[b * MAX_OUT + r] = (float)candCat[b * PRE_K + i];
    } else {
      p[0] = 0.0f; p[1] = 0.0f; p[2] = 0.0f; p[3] = 0.0f; p[4] = 0.0f;
      ocat[b * MAX_OUT + r] = 0.0f;
    }
  }
}

extern "C" void kernel_launch(void* const* d_in, const int* in_sizes, int n_in,
                              void* d_out, int out_size, void* d_ws, size_t ws_size,
                              hipStream_t stream) {
  const float* boxes = (const float*)d_in[0];
  const float* confs = (const float*)d_in[1];
  float* out = (float*)d_out;
  char* ws = (char*)d_ws;

  const size_t OFF_KHI  = 0;                            // 1 MB (u32 hi words)
  const size_t OFF_CATS = (size_t)1 << 20;              // 256 KB (u8)
  const size_t OFF_COFF = OFF_CATS + (256u << 10);      // 256 KB
  const size_t OFF_CORG = OFF_COFF + (256u << 10);      // 256 KB
  const size_t OFF_CSC  = OFF_CORG + (256u << 10);      // 64 KB
  const size_t OFF_CCAT = OFF_CSC + (64u << 10);        // 64 KB
  const size_t OFF_MASK = OFF_CCAT + (64u << 10);       // 4 MB

  u32* keyhi   = (u32*)(ws + OFF_KHI);
  u8* cats     = (u8*)(ws + OFF_CATS);
  float4* cOff = (float4*)(ws + OFF_COFF);
  float4* cOrg = (float4*)(ws + OFF_CORG);
  float* cSc   = (float*)(ws + OFF_CSC);
  int* cCat    = (int*)(ws + OFF_CCAT);
  u64* mask    = (u64*)(ws + OFF_MASK);

  k_score<<<BATCH * NANCH / 64, 256, 0, stream>>>(confs, keyhi, cats);
  k_sel<<<BATCH, 1024, 0, stream>>>(keyhi, cats, boxes, cOff, cOrg, cSc, cCat);
  dim3 g3(64, BATCH);
  k_mask<<<g3, 256, 0, stream>>>(cOff, mask);
  k_scan<<<BATCH, 64, 0, stream>>>(mask, cOrg, cSc, cCat, out);
}

// Round 11
// 101.224 us; speedup vs baseline: 3.6511x; 1.2590x over previous
//
#include <hip/hip_runtime.h>
#include <stdint.h>

#define BATCH 8
#define NANCH 32768
#define NCLS 81
#define PRE_K 2048
#define PK1 256
#define MAX_OUT 200
#define IOU_TH 0.5f
#define SCORE_TH 0.05f

typedef uint32_t u32;
typedef uint64_t u64;
typedef uint8_t u8;

__device__ __forceinline__ u32 f2sort(float f) {
  u32 u = __float_as_uint(f);
  return (u & 0x80000000u) ? ~u : (u | 0x80000000u);
}
__device__ __forceinline__ float sort2f(u32 u) {
  u = (u & 0x80000000u) ? (u & 0x7FFFFFFFu) : ~u;
  return __uint_as_float(u);
}

// ---------------- kernel 1: per-anchor max/argmax over 81 classes ----------
__global__ __launch_bounds__(256) void k_score(const float* __restrict__ confs,
                                               u32* __restrict__ keyhi,
                                               u8* __restrict__ cats) {
  __shared__ float st[64 * NCLS];
  __shared__ u32 outh[64];
  __shared__ u8 outc[64];
  int tid = threadIdx.x;
  const float4* src = (const float4*)confs + (size_t)blockIdx.x * (64 * NCLS / 4);
  float4* dst = (float4*)st;
  for (int idx = tid; idx < 64 * NCLS / 4; idx += 256) dst[idx] = src[idx];
  __syncthreads();

  int a = tid >> 2, s = tid & 3;
  const float* row = st + a * NCLS;
  int c0 = s * 20;
  int cnt = (s == 3) ? 21 : 20;
  u64 key = 0;
  for (int k = 0; k < cnt; ++k) {
    int c = c0 + k;
    u64 k2 = ((u64)__float_as_uint(row[c]) << 7) | (u32)(127 - c);
    if (k2 > key) key = k2;
  }
  u64 o = __shfl_xor(key, 1); if (o > key) key = o;
  o = __shfl_xor(key, 2); if (o > key) key = o;
  if (s == 0) {
    float v = __uint_as_float((u32)(key >> 7));
    int c = 127 - (int)(key & 127);
    bool valid = (v > SCORE_TH) && (c != 0);
    float sc = valid ? v : -1.0f;
    outh[a] = f2sort(sc);
    outc[a] = (u8)c;
  }
  __syncthreads();
  if (tid < 64) {
    int g = blockIdx.x * 64 + tid;
    keyhi[g] = outh[tid];
    cats[g] = outc[tid];
  }
}

// -------- wave-scan digit finder ---------
template <int B>
__device__ void scan_digit_fast(const u32* gh, int need, u32* sbuf,
                                int tid, int* D, int* NO) {
  const int CS = B / 256;
  if (tid < 256) {
    int hi = B - 1 - tid * CS;
    u32 s = 0;
    #pragma unroll 4
    for (int k = 0; k < CS; ++k) s += gh[hi - k];
    sbuf[tid] = s;
  }
  __syncthreads();
  if (tid < 64) {
    u32 v0 = sbuf[tid * 4], v1 = sbuf[tid * 4 + 1];
    u32 v2 = sbuf[tid * 4 + 2], v3 = sbuf[tid * 4 + 3];
    u32 loc = v0 + v1 + v2 + v3;
    u32 inc = loc;
    #pragma unroll
    for (int off = 1; off < 64; off <<= 1) {
      u32 ov = __shfl_up(inc, off);
      if (tid >= off) inc += ov;
    }
    u32 exc = inc - loc;
    if (exc < (u32)need && inc >= (u32)need) {
      int acc = (int)exc;
      u32 vs[4] = {v0, v1, v2, v3};
      #pragma unroll
      for (int c = 0; c < 4; ++c) {
        if (acc + (int)vs[c] >= need) {
          int h2 = B - 1 - (tid * 4 + c) * CS;
          for (int k = 0; k < CS; ++k) {
            u32 h = gh[h2 - k];
            acc += (int)h;
            if (acc >= need) {
              sbuf[256] = (u32)(h2 - k);
              sbuf[257] = (u32)(need - (acc - (int)h));
              break;
            }
          }
          break;
        }
        acc += (int)vs[c];
      }
    }
  }
  __syncthreads();
  *D = (int)sbuf[256];
  *NO = (int)sbuf[257];
  __syncthreads();
}

// ======== kernel 2: FUSED top-256 select + sort + mask + scan + output =====
__global__ __launch_bounds__(1024) void k_nms256(const u32* __restrict__ keyhi,
                                                 const u8* __restrict__ cats,
                                                 const float* __restrict__ boxes,
                                                 float* __restrict__ out,
                                                 u32* __restrict__ gFlag) {
  int b = blockIdx.x;
  int tid = threadIdx.x;
  int lane = tid & 63;
  __shared__ u32 hist[4096];
  __shared__ u32 sbuf[258];
  __shared__ u64 selk[PK1];
  __shared__ u64 ties[128];
  __shared__ u32 s_cnt, s_tcnt, s_nvalid;
  __shared__ float4 sbo[PK1];
  __shared__ float sar[PK1];
  __shared__ float ssc[PK1];
  __shared__ u32 sn[PK1];
  __shared__ u8 scat[PK1];
  __shared__ u64 mk[PK1][4];     // 8 KB mask
  __shared__ int keptI[MAX_OUT];
  __shared__ int s_kc;

  const uint4* bh4 = (const uint4*)(keyhi + (size_t)b * NANCH);
  uint4 hk[8];
  #pragma unroll
  for (int j = 0; j < 8; ++j) hk[j] = bh4[tid + j * 1024];

  if (tid == 0) { s_cnt = 0; s_tcnt = 0; s_nvalid = 0; }
  for (int i = tid; i < 4096; i += 1024) hist[i] = 0;
  __syncthreads();

#define ELEM(j, c) ((c) == 0 ? hk[j].x : (c) == 1 ? hk[j].y : (c) == 2 ? hk[j].z : hk[j].w)

  // pass 1: top 8 bits, warp-aggregated
  #pragma unroll
  for (int j = 0; j < 8; ++j) {
    #pragma unroll
    for (int c = 0; c < 4; ++c) {
      u32 d = ELEM(j, c) >> 24;
      u64 todo = ~0ull;
      while (todo) {
        int src = __ffsll((unsigned long long)todo) - 1;
        u32 dd = __shfl(d, src);
        u64 match = __ballot(d == dd);
        if (lane == src) atomicAdd(&hist[dd], (u32)__popcll(match));
        todo &= ~match;
      }
    }
  }
  __syncthreads();
  // nvalid = count of keys with top byte >= 0x41 (invalid key = -1.0 -> 0x40)
  if (tid >= 0x41 && tid < 256) {
    u32 v = hist[tid];
    if (v) atomicAdd(&s_nvalid, v);
  }
  int D1, n1;
  scan_digit_fast<256>(hist, PK1, sbuf, tid, &D1, &n1);

  for (int i = tid; i < 4096; i += 1024) hist[i] = 0;
  __syncthreads();

  // pass 2: next 12 bits, plain atomics
  u32 p1 = (u32)D1;
  #pragma unroll
  for (int j = 0; j < 8; ++j) {
    #pragma unroll
    for (int c = 0; c < 4; ++c) {
      u32 h = ELEM(j, c);
      if ((h >> 24) == p1) atomicAdd(&hist[(h >> 12) & 0xFFF], 1u);
    }
  }
  __syncthreads();
  int D2, n2;
  scan_digit_fast<4096>(hist, n1, sbuf, tid, &D2, &n2);

  for (int i = tid; i < 4096; i += 1024) hist[i] = 0;
  __syncthreads();

  // pass 3: low 12 bits, plain atomics
  u32 p2 = (p1 << 12) | (u32)D2;
  #pragma unroll
  for (int j = 0; j < 8; ++j) {
    #pragma unroll
    for (int c = 0; c < 4; ++c) {
      u32 h = ELEM(j, c);
      if ((h >> 12) == p2) atomicAdd(&hist[h & 0xFFF], 1u);
    }
  }
  __syncthreads();
  int D3, n3;
  scan_digit_fast<4096>(hist, n2, sbuf, tid, &D3, &n3);

  u32 S32 = (p2 << 12) | (u32)D3;
  int need3 = n3;

  // compaction (exactly PK1 - need3 strict-greater keys)
  #pragma unroll
  for (int j = 0; j < 8; ++j) {
    #pragma unroll
    for (int c = 0; c < 4; ++c) {
      u32 h = ELEM(j, c);
      u32 n = (u32)(4 * tid + 4096 * j + c);
      u64 k = ((u64)h << 32) | (u64)(0xFFFFFFFFu - n);
      bool gt = h > S32;
      u64 m = __ballot(gt);
      u32 wbase = 0;
      if (lane == 0 && m) wbase = atomicAdd(&s_cnt, (u32)__popcll(m));
      wbase = __shfl(wbase, 0);
      if (gt) {
        u32 pos = wbase + (u32)__popcll(m & ((1ull << lane) - 1));
        if (pos < PK1) selk[pos] = k;
      }
      if (h == S32) {
        u32 tp = atomicAdd(&s_tcnt, 1u);
        if (tp < 128) ties[tp] = k;
      }
    }
  }
#undef ELEM
  __syncthreads();

  int nt = (int)s_tcnt; if (nt > 128) nt = 128;
  int base = (int)s_cnt;  // == PK1 - need3
  if (tid < nt) {
    u64 my = ties[tid];
    int r = 0;
    for (int j = 0; j < nt; ++j) r += (ties[j] > my);
    if (r < need3 && base + r < PK1) selk[base + r] = my;
  }
  __syncthreads();

  // bitonic sort ascending over 256 distinct keys
  for (int k = 2; k <= PK1; k <<= 1) {
    for (int j = k >> 1; j > 0; j >>= 1) {
      if (tid < PK1) {
        int idx = tid;
        int ixj = idx ^ j;
        if (ixj > idx) {
          u64 a = selk[idx], c = selk[ixj];
          bool up = ((idx & k) == 0);
          if ((a > c) == up) { selk[idx] = c; selk[ixj] = a; }
        }
      }
      __syncthreads();
    }
  }

  // gather candidate records (rank r = selk[PK1-1-r])
  if (tid < PK1) {
    u64 my = selk[PK1 - 1 - tid];
    u32 n = 0xFFFFFFFFu - (u32)(my & 0xFFFFFFFFu);
    float s = sort2f((u32)(my >> 32));
    int cat = (int)cats[(size_t)b * NANCH + n];
    const float* bp = boxes + ((size_t)b * NANCH + n) * 4;
    float4 ob = make_float4(bp[0], bp[1], bp[2], bp[3]);
    float off = 2.0f * (float)cat;
    float4 obo = make_float4(ob.x + off, ob.y + off, ob.z + off, ob.w + off);
    sbo[tid] = obo;
    sar[tid] = fmaxf(obo.z - obo.x, 0.0f) * fmaxf(obo.w - obo.y, 0.0f);
    ssc[tid] = s;
    sn[tid] = n;
    scat[tid] = (u8)cat;
  }
  __syncthreads();

  // 256x256 mask in LDS: thread t -> row i = t>>2, word w = t&3
  {
    int i = tid >> 2, w = tid & 3;
    float4 bi = sbo[i];
    float ai = sar[i];
    u64 word = 0;
    int j0 = w * 64;
    for (int jj = 0; jj < 64; ++jj) {
      float4 bj = sbo[j0 + jj];
      float lx = fmaxf(bi.x, bj.x), ly = fmaxf(bi.y, bj.y);
      float rx = fminf(bi.z, bj.z), ry = fminf(bi.w, bj.w);
      float iw = fmaxf(rx - lx, 0.0f), ih = fmaxf(ry - ly, 0.0f);
      float inter = iw * ih;
      float uni = fmaxf(ai + sar[j0 + jj] - inter, 1e-9f);
      if (inter > 0.5f * uni) word |= (1ull << jj);
    }
    mk[i][w] = word;
  }
  __syncthreads();

  // greedy scan (wave 0); lanes 0..3 hold remv words
  if (tid < 64) {
    u64 remv = 0;
    int cnt = 0;
    for (int i = 0; i < PK1; ++i) {
      u64 wb = __shfl(remv, i >> 6);
      bool sup = (wb >> (i & 63)) & 1ull;
      if (!sup && ssc[i] > SCORE_TH) {
        if (lane == 0 && cnt < MAX_OUT) keptI[cnt] = i;
        if (lane < 4) remv |= mk[i][lane];
        cnt++;
        if (cnt >= MAX_OUT) break;
      }
    }
    if (lane == 0) {
      int kc = cnt < MAX_OUT ? cnt : MAX_OUT;
      s_kc = kc;
      u32 ok = (cnt >= MAX_OUT) || ((int)s_nvalid <= PK1);
      gFlag[b] = ok;
    }
  }
  __syncthreads();

  if (!gFlag[b]) return;  // fallback path will produce the output

  int kc = s_kc;
  float* out5 = out;
  float* ocat = out + BATCH * MAX_OUT * 5;
  for (int r = tid; r < MAX_OUT; r += 1024) {
    float* p = out5 + ((size_t)(b * MAX_OUT + r)) * 5;
    if (r < kc) {
      int i = keptI[r];
      u32 n = sn[i];
      const float* bp = boxes + ((size_t)b * NANCH + n) * 4;
      p[0] = bp[0]; p[1] = bp[1]; p[2] = bp[2]; p[3] = bp[3]; p[4] = ssc[i];
      ocat[b * MAX_OUT + r] = (float)scat[i];
    } else {
      p[0] = 0.0f; p[1] = 0.0f; p[2] = 0.0f; p[3] = 0.0f; p[4] = 0.0f;
      ocat[b * MAX_OUT + r] = 0.0f;
    }
  }
}

// ======== FALLBACK pipeline (exact R10 path, gated on !gFlag) ==============
__global__ __launch_bounds__(1024) void k_sel2048(const u32* __restrict__ keyhi,
                                                  const u8* __restrict__ cats,
                                                  const float* __restrict__ boxes,
                                                  const u32* __restrict__ gFlag,
                                                  float4* __restrict__ candOff,
                                                  float4* __restrict__ candOrig,
                                                  float* __restrict__ candScore,
                                                  int* __restrict__ candCat) {
  int b = blockIdx.x;
  if (gFlag[b]) return;
  int tid = threadIdx.x;
  int lane = tid & 63;
  __shared__ u32 hist[4096];
  __shared__ u32 sbuf[258];
  __shared__ u64 selk[PRE_K];
  __shared__ u64 ties[128];
  __shared__ u32 s_cnt, s_tcnt;

  const uint4* bh4 = (const uint4*)(keyhi + (size_t)b * NANCH);
  uint4 hk[8];
  #pragma unroll
  for (int j = 0; j < 8; ++j) hk[j] = bh4[tid + j * 1024];

  if (tid == 0) { s_cnt = 0; s_tcnt = 0; }
  for (int i = tid; i < 4096; i += 1024) hist[i] = 0;
  __syncthreads();

#define ELEM(j, c) ((c) == 0 ? hk[j].x : (c) == 1 ? hk[j].y : (c) == 2 ? hk[j].z : hk[j].w)
  #pragma unroll
  for (int j = 0; j < 8; ++j) {
    #pragma unroll
    for (int c = 0; c < 4; ++c) {
      u32 d = ELEM(j, c) >> 24;
      u64 todo = ~0ull;
      while (todo) {
        int src = __ffsll((unsigned long long)todo) - 1;
        u32 dd = __shfl(d, src);
        u64 match = __ballot(d == dd);
        if (lane == src) atomicAdd(&hist[dd], (u32)__popcll(match));
        todo &= ~match;
      }
    }
  }
  __syncthreads();
  int D1, n1;
  scan_digit_fast<256>(hist, PRE_K, sbuf, tid, &D1, &n1);

  for (int i = tid; i < 4096; i += 1024) hist[i] = 0;
  __syncthreads();
  u32 p1 = (u32)D1;
  #pragma unroll
  for (int j = 0; j < 8; ++j) {
    #pragma unroll
    for (int c = 0; c < 4; ++c) {
      u32 h = ELEM(j, c);
      if ((h >> 24) == p1) atomicAdd(&hist[(h >> 12) & 0xFFF], 1u);
    }
  }
  __syncthreads();
  int D2, n2;
  scan_digit_fast<4096>(hist, n1, sbuf, tid, &D2, &n2);

  for (int i = tid; i < 4096; i += 1024) hist[i] = 0;
  __syncthreads();
  u32 p2 = (p1 << 12) | (u32)D2;
  #pragma unroll
  for (int j = 0; j < 8; ++j) {
    #pragma unroll
    for (int c = 0; c < 4; ++c) {
      u32 h = ELEM(j, c);
      if ((h >> 12) == p2) atomicAdd(&hist[h & 0xFFF], 1u);
    }
  }
  __syncthreads();
  int D3, n3;
  scan_digit_fast<4096>(hist, n2, sbuf, tid, &D3, &n3);

  u32 S32 = (p2 << 12) | (u32)D3;
  int need3 = n3;

  #pragma unroll
  for (int j = 0; j < 8; ++j) {
    #pragma unroll
    for (int c = 0; c < 4; ++c) {
      u32 h = ELEM(j, c);
      u32 n = (u32)(4 * tid + 4096 * j + c);
      u64 k = ((u64)h << 32) | (u64)(0xFFFFFFFFu - n);
      bool gt = h > S32;
      u64 m = __ballot(gt);
      u32 wbase = 0;
      if (lane == 0 && m) wbase = atomicAdd(&s_cnt, (u32)__popcll(m));
      wbase = __shfl(wbase, 0);
      if (gt) {
        u32 pos = wbase + (u32)__popcll(m & ((1ull << lane) - 1));
        if (pos < PRE_K) selk[pos] = k;
      }
      if (h == S32) {
        u32 tp = atomicAdd(&s_tcnt, 1u);
        if (tp < 128) ties[tp] = k;
      }
    }
  }
#undef ELEM
  __syncthreads();

  int nt = (int)s_tcnt; if (nt > 128) nt = 128;
  int base = (int)s_cnt;
  if (tid < nt) {
    u64 my = ties[tid];
    int r = 0;
    for (int j = 0; j < nt; ++j) r += (ties[j] > my);
    if (r < need3 && base + r < PRE_K) selk[base + r] = my;
  }
  __syncthreads();

  for (int k = 2; k <= PRE_K; k <<= 1) {
    for (int j = k >> 1; j > 0; j >>= 1) {
      for (int idx = tid; idx < PRE_K; idx += 1024) {
        int ixj = idx ^ j;
        if (ixj > idx) {
          u64 a = selk[idx], c = selk[ixj];
          bool up = ((idx & k) == 0);
          if ((a > c) == up) { selk[idx] = c; selk[ixj] = a; }
        }
      }
      __syncthreads();
    }
  }

  for (int r = tid; r < PRE_K; r += 1024) {
    u64 my = selk[PRE_K - 1 - r];
    u32 n = 0xFFFFFFFFu - (u32)(my & 0xFFFFFFFFu);
    float s = sort2f((u32)(my >> 32));
    int cat = (int)cats[(size_t)b * NANCH + n];
    const float* bp = boxes + ((size_t)b * NANCH + n) * 4;
    float4 ob = make_float4(bp[0], bp[1], bp[2], bp[3]);
    float off = 2.0f * (float)cat;
    float4 obo = make_float4(ob.x + off, ob.y + off, ob.z + off, ob.w + off);
    int o = b * PRE_K + r;
    candOff[o] = obo;
    candOrig[o] = ob;
    candScore[o] = s;
    candCat[o] = cat;
  }
}

__global__ __launch_bounds__(256) void k_mask2048(const float4* __restrict__ candOff,
                                                  const u32* __restrict__ gFlag,
                                                  u64* __restrict__ mask) {
  int b = blockIdx.y;
  if (gFlag[b]) return;
  int tid = threadIdx.x;
  int wave = tid >> 6, lane = tid & 63;
  __shared__ float4 sb[PRE_K];
  __shared__ float sarea[PRE_K];
  for (int j = tid; j < PRE_K; j += 256) {
    float4 v = candOff[b * PRE_K + j];
    sb[j] = v;
    sarea[j] = fmaxf(v.z - v.x, 0.0f) * fmaxf(v.w - v.y, 0.0f);
  }
  __syncthreads();

  int gw = blockIdx.x * 4 + wave;
  for (int k = 0; k < PRE_K / 256; ++k) {
    int i = gw + 256 * k;
    float4 bi = sb[i];
    float ai = sarea[i];
    int c0 = i >> 6;
    u64 myword = 0;
    for (int c = c0; c < 32; ++c) {
      float4 bj = sb[c * 64 + lane];
      float aj = sarea[c * 64 + lane];
      float lx = fmaxf(bi.x, bj.x), ly = fmaxf(bi.y, bj.y);
      float rx = fminf(bi.z, bj.z), ry = fminf(bi.w, bj.w);
      float iw = fmaxf(rx - lx, 0.0f), ih = fmaxf(ry - ly, 0.0f);
      float inter = iw * ih;
      float uni = fmaxf(ai + aj - inter, 1e-9f);
      u64 word = __ballot(inter > 0.5f * uni);
      if (lane == c) myword = word;
    }
    if (lane < 32) mask[((size_t)(b * PRE_K + i)) * 32 + lane] = myword;
  }
}

__global__ __launch_bounds__(64) void k_scan2048(const u64* __restrict__ mask,
                                                 const float4* __restrict__ candOrig,
                                                 const float* __restrict__ candScore,
                                                 const int* __restrict__ candCat,
                                                 const u32* __restrict__ gFlag,
                                                 float* __restrict__ out) {
  int b = blockIdx.x;
  if (gFlag[b]) return;
  int tid = threadIdx.x;
  __shared__ float ssc[PRE_K];
  __shared__ int keptI[MAX_OUT];
  for (int j = tid; j < PRE_K; j += 64) ssc[j] = candScore[b * PRE_K + j];
  __syncthreads();

  const u64* mrow = mask + (size_t)b * PRE_K * 32;
  int wsel = tid & 31;
  bool lo32 = tid < 32;
  u64 remv = 0;
  int cnt = 0;

  u64 c0=0,c1=0,c2=0,c3=0,c4=0,c5=0,c6=0,c7=0;
  if (lo32) {
    c0 = mrow[0 * 32 + wsel]; c1 = mrow[1 * 32 + wsel];
    c2 = mrow[2 * 32 + wsel]; c3 = mrow[3 * 32 + wsel];
    c4 = mrow[4 * 32 + wsel]; c5 = mrow[5 * 32 + wsel];
    c6 = mrow[6 * 32 + wsel]; c7 = mrow[7 * 32 + wsel];
  }

#define PROCESS(I, RK)                                   \
  {                                                      \
    u64 wb = __shfl(remv, (I) >> 6);                     \
    bool sup = (wb >> ((I) & 63)) & 1ull;                \
    if (!sup && ssc[I] > SCORE_TH) {                     \
      if (tid == 0 && cnt < MAX_OUT) keptI[cnt] = (I);   \
      if (lo32) remv |= (RK);                            \
      cnt++;                                             \
    }                                                    \
  }

  for (int base = 0; base < PRE_K; base += 8) {
    u64 n0=0,n1=0,n2=0,n3=0,n4=0,n5=0,n6=0,n7=0;
    if (base + 8 < PRE_K && lo32) {
      const u64* nr = mrow + (size_t)(base + 8) * 32 + wsel;
      n0 = nr[0 * 32]; n1 = nr[1 * 32]; n2 = nr[2 * 32]; n3 = nr[3 * 32];
      n4 = nr[4 * 32]; n5 = nr[5 * 32]; n6 = nr[6 * 32]; n7 = nr[7 * 32];
    }
    PROCESS(base + 0, c0); PROCESS(base + 1, c1);
    PROCESS(base + 2, c2); PROCESS(base + 3, c3);
    PROCESS(base + 4, c4); PROCESS(base + 5, c5);
    PROCESS(base + 6, c6); PROCESS(base + 7, c7);
    c0=n0; c1=n1; c2=n2; c3=n3; c4=n4; c5=n5; c6=n6; c7=n7;
    if (cnt >= MAX_OUT) break;
  }
#undef PROCESS

  int kc = cnt < MAX_OUT ? cnt : MAX_OUT;
  __syncthreads();

  float* out5 = out;
  float* ocat = out + BATCH * MAX_OUT * 5;
  for (int r = tid; r < MAX_OUT; r += 64) {
    float* p = out5 + ((size_t)(b * MAX_OUT + r)) * 5;
    if (r < kc) {
      int i = keptI[r];
      float4 ob = candOrig[b * PRE_K + i];
      p[0] = ob.x; p[1] = ob.y; p[2] = ob.z; p[3] = ob.w; p[4] = ssc[i];
      ocat[b * MAX_OUT + r] = (float)candCat[b * PRE_K + i];
    } else {
      p[0] = 0.0f; p[1] = 0.0f; p[2] = 0.0f; p[3] = 0.0f; p[4] = 0.0f;
      ocat[b * MAX_OUT + r] = 0.0f;
    }
  }
}

extern "C" void kernel_launch(void* const* d_in, const int* in_sizes, int n_in,
                              void* d_out, int out_size, void* d_ws, size_t ws_size,
                              hipStream_t stream) {
  const float* boxes = (const float*)d_in[0];
  const float* confs = (const float*)d_in[1];
  float* out = (float*)d_out;
  char* ws = (char*)d_ws;

  const size_t OFF_KHI  = 0;                            // 1 MB
  const size_t OFF_CATS = (size_t)1 << 20;              // 256 KB
  const size_t OFF_FLAG = OFF_CATS + (256u << 10);      // 64 B
  const size_t OFF_COFF = OFF_FLAG + 1024;              // 256 KB
  const size_t OFF_CORG = OFF_COFF + (256u << 10);      // 256 KB
  const size_t OFF_CSC  = OFF_CORG + (256u << 10);      // 64 KB
  const size_t OFF_CCAT = OFF_CSC + (64u << 10);        // 64 KB
  const size_t OFF_MASK = OFF_CCAT + (64u << 10);       // 4 MB

  u32* keyhi   = (u32*)(ws + OFF_KHI);
  u8* cats     = (u8*)(ws + OFF_CATS);
  u32* gFlag   = (u32*)(ws + OFF_FLAG);
  float4* cOff = (float4*)(ws + OFF_COFF);
  float4* cOrg = (float4*)(ws + OFF_CORG);
  float* cSc   = (float*)(ws + OFF_CSC);
  int* cCat    = (int*)(ws + OFF_CCAT);
  u64* mask    = (u64*)(ws + OFF_MASK);

  k_score<<<BATCH * NANCH / 64, 256, 0, stream>>>(confs, keyhi, cats);
  k_nms256<<<BATCH, 1024, 0, stream>>>(keyhi, cats, boxes, out, gFlag);
  // fallback (exact 2048 path), no-ops when gFlag[b] == 1
  k_sel2048<<<BATCH, 1024, 0, stream>>>(keyhi, cats, boxes, gFlag, cOff, cOrg, cSc, cCat);
  dim3 g3(64, BATCH);
  k_mask2048<<<g3, 256, 0, stream>>>(cOff, gFlag, mask);
  k_scan2048<<<BATCH, 64, 0, stream>>>(mask, cOrg, cSc, cCat, gFlag, out);
}

// Round 12
// 82.956 us; speedup vs baseline: 4.4551x; 1.2202x over previous
//
#include <hip/hip_runtime.h>
#include <stdint.h>

#define BATCH 8
#define NANCH 32768
#define NCLS 81
#define PRE_K 2048
#define PK1 256
#define MAX_OUT 200
#define IOU_TH 0.5f
#define SCORE_TH 0.05f

typedef uint32_t u32;
typedef uint64_t u64;
typedef uint8_t u8;

__device__ __forceinline__ u32 f2sort(float f) {
  u32 u = __float_as_uint(f);
  return (u & 0x80000000u) ? ~u : (u | 0x80000000u);
}
__device__ __forceinline__ float sort2f(u32 u) {
  u = (u & 0x80000000u) ? (u & 0x7FFFFFFFu) : ~u;
  return __uint_as_float(u);
}
__device__ __forceinline__ u64 shfl_xor64(u64 x, int m) {
  u32 lo = (u32)__shfl_xor((int)(u32)x, m);
  u32 hi = (u32)__shfl_xor((int)(u32)(x >> 32), m);
  return ((u64)hi << 32) | lo;
}

// ---------------- kernel 1: per-anchor max/argmax over 81 classes ----------
__global__ __launch_bounds__(256) void k_score(const float* __restrict__ confs,
                                               u32* __restrict__ keyhi,
                                               u8* __restrict__ cats) {
  __shared__ float st[64 * NCLS];
  __shared__ u32 outh[64];
  __shared__ u8 outc[64];
  int tid = threadIdx.x;
  const float4* src = (const float4*)confs + (size_t)blockIdx.x * (64 * NCLS / 4);
  float4* dst = (float4*)st;
  for (int idx = tid; idx < 64 * NCLS / 4; idx += 256) dst[idx] = src[idx];
  __syncthreads();

  int a = tid >> 2, s = tid & 3;
  const float* row = st + a * NCLS;
  int c0 = s * 20;
  int cnt = (s == 3) ? 21 : 20;
  u64 key = 0;
  for (int k = 0; k < cnt; ++k) {
    int c = c0 + k;
    u64 k2 = ((u64)__float_as_uint(row[c]) << 7) | (u32)(127 - c);
    if (k2 > key) key = k2;
  }
  u64 o = __shfl_xor(key, 1); if (o > key) key = o;
  o = __shfl_xor(key, 2); if (o > key) key = o;
  if (s == 0) {
    float v = __uint_as_float((u32)(key >> 7));
    int c = 127 - (int)(key & 127);
    bool valid = (v > SCORE_TH) && (c != 0);
    float sc = valid ? v : -1.0f;
    outh[a] = f2sort(sc);
    outc[a] = (u8)c;
  }
  __syncthreads();
  if (tid < 64) {
    int g = blockIdx.x * 64 + tid;
    keyhi[g] = outh[tid];
    cats[g] = outc[tid];
  }
}

// -------- wave-scan digit finder ---------
template <int B>
__device__ void scan_digit_fast(const u32* gh, int need, u32* sbuf,
                                int tid, int* D, int* NO) {
  const int CS = B / 256;
  if (tid < 256) {
    int hi = B - 1 - tid * CS;
    u32 s = 0;
    #pragma unroll 4
    for (int k = 0; k < CS; ++k) s += gh[hi - k];
    sbuf[tid] = s;
  }
  __syncthreads();
  if (tid < 64) {
    u32 v0 = sbuf[tid * 4], v1 = sbuf[tid * 4 + 1];
    u32 v2 = sbuf[tid * 4 + 2], v3 = sbuf[tid * 4 + 3];
    u32 loc = v0 + v1 + v2 + v3;
    u32 inc = loc;
    #pragma unroll
    for (int off = 1; off < 64; off <<= 1) {
      u32 ov = __shfl_up(inc, off);
      if (tid >= off) inc += ov;
    }
    u32 exc = inc - loc;
    if (exc < (u32)need && inc >= (u32)need) {
      int acc = (int)exc;
      u32 vs[4] = {v0, v1, v2, v3};
      #pragma unroll
      for (int c = 0; c < 4; ++c) {
        if (acc + (int)vs[c] >= need) {
          int h2 = B - 1 - (tid * 4 + c) * CS;
          for (int k = 0; k < CS; ++k) {
            u32 h = gh[h2 - k];
            acc += (int)h;
            if (acc >= need) {
              sbuf[256] = (u32)(h2 - k);
              sbuf[257] = (u32)(need - (acc - (int)h));
              break;
            }
          }
          break;
        }
        acc += (int)vs[c];
      }
    }
  }
  __syncthreads();
  *D = (int)sbuf[256];
  *NO = (int)sbuf[257];
  __syncthreads();
}

// ======== kernel 2: FUSED top-256 select + reg-sort + mask + scan + out ====
__global__ __launch_bounds__(1024) void k_nms256(const u32* __restrict__ keyhi,
                                                 const u8* __restrict__ cats,
                                                 const float* __restrict__ boxes,
                                                 float* __restrict__ out,
                                                 u32* __restrict__ gFlag) {
  int b = blockIdx.x;
  int tid = threadIdx.x;
  int lane = tid & 63;
  __shared__ u32 hist[4096];
  __shared__ u32 sbuf[258];
  __shared__ u64 selk[PK1];
  __shared__ u64 ties[128];
  __shared__ u32 s_cnt, s_tcnt, s_nvalid, s_ok;
  __shared__ int s_kc;
  __shared__ u32 sn_s[PK1];
  __shared__ float ssc_s[PK1];
  __shared__ float4 sbo_s[PK1];   // offset boxes (sorted)
  __shared__ float4 sorg_s[PK1];  // original boxes (sorted)
  __shared__ float sar_s[PK1];
  __shared__ u8 scat_s[PK1];
  __shared__ u64 mk[PK1][4];      // 8 KB mask
  __shared__ int keptI[MAX_OUT];

  const uint4* bh4 = (const uint4*)(keyhi + (size_t)b * NANCH);
  uint4 hk[8];
  #pragma unroll
  for (int j = 0; j < 8; ++j) hk[j] = bh4[tid + j * 1024];

  if (tid == 0) { s_cnt = 0; s_tcnt = 0; s_nvalid = 0; }
  for (int i = tid; i < 4096; i += 1024) hist[i] = 0;
  __syncthreads();

#define ELEM(j, c) ((c) == 0 ? hk[j].x : (c) == 1 ? hk[j].y : (c) == 2 ? hk[j].z : hk[j].w)

  // pass 1: top 8 bits, warp-aggregated
  #pragma unroll
  for (int j = 0; j < 8; ++j) {
    #pragma unroll
    for (int c = 0; c < 4; ++c) {
      u32 d = ELEM(j, c) >> 24;
      u64 todo = ~0ull;
      while (todo) {
        int src = __ffsll((unsigned long long)todo) - 1;
        u32 dd = __shfl(d, src);
        u64 match = __ballot(d == dd);
        if (lane == src) atomicAdd(&hist[dd], (u32)__popcll(match));
        todo &= ~match;
      }
    }
  }
  __syncthreads();
  // nvalid = count of keys with top byte >= 0x41 (invalid key -1.0 -> 0x40)
  if (tid >= 0x41 && tid < 256) {
    u32 v = hist[tid];
    if (v) atomicAdd(&s_nvalid, v);
  }
  int D1, n1;
  scan_digit_fast<256>(hist, PK1, sbuf, tid, &D1, &n1);

  for (int i = tid; i < 4096; i += 1024) hist[i] = 0;
  __syncthreads();

  // pass 2: next 12 bits
  u32 p1 = (u32)D1;
  #pragma unroll
  for (int j = 0; j < 8; ++j) {
    #pragma unroll
    for (int c = 0; c < 4; ++c) {
      u32 h = ELEM(j, c);
      if ((h >> 24) == p1) atomicAdd(&hist[(h >> 12) & 0xFFF], 1u);
    }
  }
  __syncthreads();
  int D2, n2;
  scan_digit_fast<4096>(hist, n1, sbuf, tid, &D2, &n2);

  for (int i = tid; i < 4096; i += 1024) hist[i] = 0;
  __syncthreads();

  // pass 3: low 12 bits
  u32 p2 = (p1 << 12) | (u32)D2;
  #pragma unroll
  for (int j = 0; j < 8; ++j) {
    #pragma unroll
    for (int c = 0; c < 4; ++c) {
      u32 h = ELEM(j, c);
      if ((h >> 12) == p2) atomicAdd(&hist[h & 0xFFF], 1u);
    }
  }
  __syncthreads();
  int D3, n3;
  scan_digit_fast<4096>(hist, n2, sbuf, tid, &D3, &n3);

  u32 S32 = (p2 << 12) | (u32)D3;
  int need3 = n3;

  // compaction (exactly PK1 - need3 strict-greater keys)
  #pragma unroll
  for (int j = 0; j < 8; ++j) {
    #pragma unroll
    for (int c = 0; c < 4; ++c) {
      u32 h = ELEM(j, c);
      u32 n = (u32)(4 * tid + 4096 * j + c);
      u64 k = ((u64)h << 32) | (u64)(0xFFFFFFFFu - n);
      bool gt = h > S32;
      u64 m = __ballot(gt);
      u32 wbase = 0;
      if (lane == 0 && m) wbase = atomicAdd(&s_cnt, (u32)__popcll(m));
      wbase = __shfl(wbase, 0);
      if (gt) {
        u32 pos = wbase + (u32)__popcll(m & ((1ull << lane) - 1));
        if (pos < PK1) selk[pos] = k;
      }
      if (h == S32) {
        u32 tp = atomicAdd(&s_tcnt, 1u);
        if (tp < 128) ties[tp] = k;
      }
    }
  }
#undef ELEM
  __syncthreads();

  {
    int nt = (int)s_tcnt; if (nt > 128) nt = 128;
    int base = (int)s_cnt;  // == PK1 - need3
    if (tid < nt) {
      u64 my = ties[tid];
      int r = 0;
      for (int j = 0; j < nt; ++j) r += (ties[j] > my);
      if (r < need3 && base + r < PK1) selk[base + r] = my;
    }
  }
  __syncthreads();

  // ---- in-register bitonic sort of 256 keys in wave 0 (no barriers) ------
  if (tid < 64) {
    u64 v0 = selk[lane], v1 = selk[64 + lane], v2 = selk[128 + lane], v3 = selk[192 + lane];

#define CAS_REG(A, B, UP) { u64 ta = A, tb = B; if ((ta > tb) == (UP)) { A = tb; B = ta; } }
#define CAS_SHF(R, J, UP) { u64 o = shfl_xor64(R, (J)); bool tm = (((lane & (J)) == 0) == (UP)); \
                            u64 mn = (o < R) ? o : R; u64 mx = (o < R) ? R : o; R = tm ? mn : mx; }

    // k = 2..32 : up depends on lane only
    #pragma unroll
    for (int k = 2; k <= 32; k <<= 1) {
      #pragma unroll
      for (int j = k >> 1; j > 0; j >>= 1) {
        bool u0 = (lane & k) == 0;
        CAS_SHF(v0, j, u0) CAS_SHF(v1, j, u0) CAS_SHF(v2, j, u0) CAS_SHF(v3, j, u0)
      }
    }
    // k = 64 : up depends on register parity
    #pragma unroll
    for (int j = 32; j > 0; j >>= 1) {
      CAS_SHF(v0, j, true) CAS_SHF(v1, j, false) CAS_SHF(v2, j, true) CAS_SHF(v3, j, false)
    }
    // k = 128 : j=64 register exchange, then shfl stages (up by r&2)
    CAS_REG(v0, v1, true) CAS_REG(v2, v3, false)
    #pragma unroll
    for (int j = 32; j > 0; j >>= 1) {
      CAS_SHF(v0, j, true) CAS_SHF(v1, j, true) CAS_SHF(v2, j, false) CAS_SHF(v3, j, false)
    }
    // k = 256 : j=128, j=64 register exchanges, then shfl stages (up=true)
    CAS_REG(v0, v2, true) CAS_REG(v1, v3, true)
    CAS_REG(v0, v1, true) CAS_REG(v2, v3, true)
    #pragma unroll
    for (int j = 32; j > 0; j >>= 1) {
      CAS_SHF(v0, j, true) CAS_SHF(v1, j, true) CAS_SHF(v2, j, true) CAS_SHF(v3, j, true)
    }
#undef CAS_REG
#undef CAS_SHF

    // ascending rank e = r*64+lane; descending rank d = 255-e
    #pragma unroll
    for (int r = 0; r < 4; ++r) {
      u64 key = (r == 0) ? v0 : (r == 1) ? v1 : (r == 2) ? v2 : v3;
      int d = 255 - (r * 64 + lane);
      sn_s[d] = 0xFFFFFFFFu - (u32)key;
      ssc_s[d] = sort2f((u32)(key >> 32));
    }
  }
  __syncthreads();

  // ---- gather boxes/cats in sorted order (256 threads) --------------------
  if (tid < PK1) {
    u32 n = sn_s[tid];
    int cat = (int)cats[(size_t)b * NANCH + n];
    const float* bp = boxes + ((size_t)b * NANCH + n) * 4;
    float4 ob = make_float4(bp[0], bp[1], bp[2], bp[3]);
    float off = 2.0f * (float)cat;
    float4 obo = make_float4(ob.x + off, ob.y + off, ob.z + off, ob.w + off);
    sorg_s[tid] = ob;
    sbo_s[tid] = obo;
    sar_s[tid] = fmaxf(obo.z - obo.x, 0.0f) * fmaxf(obo.w - obo.y, 0.0f);
    scat_s[tid] = (u8)cat;
  }
  __syncthreads();

  // ---- 256x256 mask in LDS: thread t -> row i = t>>2, word w = t&3 --------
  {
    int i = tid >> 2, w = tid & 3;
    float4 bi = sbo_s[i];
    float ai = sar_s[i];
    u64 word = 0;
    int j0 = w * 64;
    for (int jj = 0; jj < 64; ++jj) {
      float4 bj = sbo_s[j0 + jj];
      float lx = fmaxf(bi.x, bj.x), ly = fmaxf(bi.y, bj.y);
      float rx = fminf(bi.z, bj.z), ry = fminf(bi.w, bj.w);
      float iw = fmaxf(rx - lx, 0.0f), ih = fmaxf(ry - ly, 0.0f);
      float inter = iw * ih;
      float uni = fmaxf(ai + sar_s[j0 + jj] - inter, 1e-9f);
      if (inter > 0.5f * uni) word |= (1ull << jj);
    }
    mk[i][w] = word;
  }
  __syncthreads();

  // ---- greedy scan, wave 0, 8-deep register prefetch from LDS -------------
  if (tid < 64) {
    bool l4 = lane < 4;
    u64 remv = 0;
    int cnt = 0;
    u64 m0=0,m1=0,m2=0,m3=0,m4=0,m5=0,m6=0,m7=0;
    float s0, s1, s2, s3, s4, s5, s6, s7;
    if (l4) {
      m0 = mk[0][lane]; m1 = mk[1][lane]; m2 = mk[2][lane]; m3 = mk[3][lane];
      m4 = mk[4][lane]; m5 = mk[5][lane]; m6 = mk[6][lane]; m7 = mk[7][lane];
    }
    s0 = ssc_s[0]; s1 = ssc_s[1]; s2 = ssc_s[2]; s3 = ssc_s[3];
    s4 = ssc_s[4]; s5 = ssc_s[5]; s6 = ssc_s[6]; s7 = ssc_s[7];

#define PROC(D)                                                       \
    {                                                                 \
      int i = base + (D);                                             \
      u64 wb = __shfl(remv, i >> 6);                                  \
      bool sup = (wb >> (i & 63)) & 1ull;                             \
      if (!sup && s##D > SCORE_TH) {                                  \
        if (lane == 0 && cnt < MAX_OUT) keptI[cnt] = i;               \
        if (l4) remv |= m##D;                                         \
        cnt++;                                                        \
      }                                                               \
    }

    for (int base = 0; base < PK1; base += 8) {
      u64 t0=0,t1=0,t2=0,t3=0,t4=0,t5=0,t6=0,t7=0;
      float u0=0,u1=0,u2=0,u3=0,u4=0,u5=0,u6=0,u7=0;
      if (base + 8 < PK1) {
        int nb = base + 8;
        if (l4) {
          t0 = mk[nb+0][lane]; t1 = mk[nb+1][lane]; t2 = mk[nb+2][lane]; t3 = mk[nb+3][lane];
          t4 = mk[nb+4][lane]; t5 = mk[nb+5][lane]; t6 = mk[nb+6][lane]; t7 = mk[nb+7][lane];
        }
        u0 = ssc_s[nb+0]; u1 = ssc_s[nb+1]; u2 = ssc_s[nb+2]; u3 = ssc_s[nb+3];
        u4 = ssc_s[nb+4]; u5 = ssc_s[nb+5]; u6 = ssc_s[nb+6]; u7 = ssc_s[nb+7];
      }
      PROC(0) PROC(1) PROC(2) PROC(3) PROC(4) PROC(5) PROC(6) PROC(7)
      m0=t0; m1=t1; m2=t2; m3=t3; m4=t4; m5=t5; m6=t6; m7=t7;
      s0=u0; s1=u1; s2=u2; s3=u3; s4=u4; s5=u5; s6=u6; s7=u7;
      if (cnt >= MAX_OUT) break;
    }
#undef PROC

    if (lane == 0) {
      s_kc = cnt < MAX_OUT ? cnt : MAX_OUT;
      u32 ok = (cnt >= MAX_OUT) || ((int)s_nvalid <= PK1);
      s_ok = ok;
      gFlag[b] = ok;
    }
  }
  __syncthreads();

  if (!s_ok) return;  // fallback path will produce the output

  int kc = s_kc;
  float* out5 = out;
  float* ocat = out + BATCH * MAX_OUT * 5;
  for (int r = tid; r < MAX_OUT; r += 1024) {
    float* p = out5 + ((size_t)(b * MAX_OUT + r)) * 5;
    if (r < kc) {
      int i = keptI[r];
      float4 ob = sorg_s[i];
      p[0] = ob.x; p[1] = ob.y; p[2] = ob.z; p[3] = ob.w; p[4] = ssc_s[i];
      ocat[b * MAX_OUT + r] = (float)scat_s[i];
    } else {
      p[0] = 0.0f; p[1] = 0.0f; p[2] = 0.0f; p[3] = 0.0f; p[4] = 0.0f;
      ocat[b * MAX_OUT + r] = 0.0f;
    }
  }
}

// ======== FALLBACK pipeline (exact R10 path, gated on !gFlag) ==============
__global__ __launch_bounds__(1024) void k_sel2048(const u32* __restrict__ keyhi,
                                                  const u8* __restrict__ cats,
                                                  const float* __restrict__ boxes,
                                                  const u32* __restrict__ gFlag,
                                                  float4* __restrict__ candOff,
                                                  float4* __restrict__ candOrig,
                                                  float* __restrict__ candScore,
                                                  int* __restrict__ candCat) {
  int b = blockIdx.x;
  if (gFlag[b]) return;
  int tid = threadIdx.x;
  int lane = tid & 63;
  __shared__ u32 hist[4096];
  __shared__ u32 sbuf[258];
  __shared__ u64 selk[PRE_K];
  __shared__ u64 ties[128];
  __shared__ u32 s_cnt, s_tcnt;

  const uint4* bh4 = (const uint4*)(keyhi + (size_t)b * NANCH);
  uint4 hk[8];
  #pragma unroll
  for (int j = 0; j < 8; ++j) hk[j] = bh4[tid + j * 1024];

  if (tid == 0) { s_cnt = 0; s_tcnt = 0; }
  for (int i = tid; i < 4096; i += 1024) hist[i] = 0;
  __syncthreads();

#define ELEM(j, c) ((c) == 0 ? hk[j].x : (c) == 1 ? hk[j].y : (c) == 2 ? hk[j].z : hk[j].w)
  #pragma unroll
  for (int j = 0; j < 8; ++j) {
    #pragma unroll
    for (int c = 0; c < 4; ++c) {
      u32 d = ELEM(j, c) >> 24;
      u64 todo = ~0ull;
      while (todo) {
        int src = __ffsll((unsigned long long)todo) - 1;
        u32 dd = __shfl(d, src);
        u64 match = __ballot(d == dd);
        if (lane == src) atomicAdd(&hist[dd], (u32)__popcll(match));
        todo &= ~match;
      }
    }
  }
  __syncthreads();
  int D1, n1;
  scan_digit_fast<256>(hist, PRE_K, sbuf, tid, &D1, &n1);

  for (int i = tid; i < 4096; i += 1024) hist[i] = 0;
  __syncthreads();
  u32 p1 = (u32)D1;
  #pragma unroll
  for (int j = 0; j < 8; ++j) {
    #pragma unroll
    for (int c = 0; c < 4; ++c) {
      u32 h = ELEM(j, c);
      if ((h >> 24) == p1) atomicAdd(&hist[(h >> 12) & 0xFFF], 1u);
    }
  }
  __syncthreads();
  int D2, n2;
  scan_digit_fast<4096>(hist, n1, sbuf, tid, &D2, &n2);

  for (int i = tid; i < 4096; i += 1024) hist[i] = 0;
  __syncthreads();
  u32 p2 = (p1 << 12) | (u32)D2;
  #pragma unroll
  for (int j = 0; j < 8; ++j) {
    #pragma unroll
    for (int c = 0; c < 4; ++c) {
      u32 h = ELEM(j, c);
      if ((h >> 12) == p2) atomicAdd(&hist[h & 0xFFF], 1u);
    }
  }
  __syncthreads();
  int D3, n3;
  scan_digit_fast<4096>(hist, n2, sbuf, tid, &D3, &n3);

  u32 S32 = (p2 << 12) | (u32)D3;
  int need3 = n3;

  #pragma unroll
  for (int j = 0; j < 8; ++j) {
    #pragma unroll
    for (int c = 0; c < 4; ++c) {
      u32 h = ELEM(j, c);
      u32 n = (u32)(4 * tid + 4096 * j + c);
      u64 k = ((u64)h << 32) | (u64)(0xFFFFFFFFu - n);
      bool gt = h > S32;
      u64 m = __ballot(gt);
      u32 wbase = 0;
      if (lane == 0 && m) wbase = atomicAdd(&s_cnt, (u32)__popcll(m));
      wbase = __shfl(wbase, 0);
      if (gt) {
        u32 pos = wbase + (u32)__popcll(m & ((1ull << lane) - 1));
        if (pos < PRE_K) selk[pos] = k;
      }
      if (h == S32) {
        u32 tp = atomicAdd(&s_tcnt, 1u);
        if (tp < 128) ties[tp] = k;
      }
    }
  }
#undef ELEM
  __syncthreads();

  int nt = (int)s_tcnt; if (nt > 128) nt = 128;
  int base = (int)s_cnt;
  if (tid < nt) {
    u64 my = ties[tid];
    int r = 0;
    for (int j = 0; j < nt; ++j) r += (ties[j] > my);
    if (r < need3 && base + r < PRE_K) selk[base + r] = my;
  }
  __syncthreads();

  for (int k = 2; k <= PRE_K; k <<= 1) {
    for (int j = k >> 1; j > 0; j >>= 1) {
      for (int idx = tid; idx < PRE_K; idx += 1024) {
        int ixj = idx ^ j;
        if (ixj > idx) {
          u64 a = selk[idx], c = selk[ixj];
          bool up = ((idx & k) == 0);
          if ((a > c) == up) { selk[idx] = c; selk[ixj] = a; }
        }
      }
      __syncthreads();
    }
  }

  for (int r = tid; r < PRE_K; r += 1024) {
    u64 my = selk[PRE_K - 1 - r];
    u32 n = 0xFFFFFFFFu - (u32)(my & 0xFFFFFFFFu);
    float s = sort2f((u32)(my >> 32));
    int cat = (int)cats[(size_t)b * NANCH + n];
    const float* bp = boxes + ((size_t)b * NANCH + n) * 4;
    float4 ob = make_float4(bp[0], bp[1], bp[2], bp[3]);
    float off = 2.0f * (float)cat;
    float4 obo = make_float4(ob.x + off, ob.y + off, ob.z + off, ob.w + off);
    int o = b * PRE_K + r;
    candOff[o] = obo;
    candOrig[o] = ob;
    candScore[o] = s;
    candCat[o] = cat;
  }
}

__global__ __launch_bounds__(256) void k_mask2048(const float4* __restrict__ candOff,
                                                  const u32* __restrict__ gFlag,
                                                  u64* __restrict__ mask) {
  int b = blockIdx.y;
  if (gFlag[b]) return;
  int tid = threadIdx.x;
  int wave = tid >> 6, lane = tid & 63;
  __shared__ float4 sb[PRE_K];
  __shared__ float sarea[PRE_K];
  for (int j = tid; j < PRE_K; j += 256) {
    float4 v = candOff[b * PRE_K + j];
    sb[j] = v;
    sarea[j] = fmaxf(v.z - v.x, 0.0f) * fmaxf(v.w - v.y, 0.0f);
  }
  __syncthreads();

  int gw = blockIdx.x * 4 + wave;
  for (int k = 0; k < PRE_K / 256; ++k) {
    int i = gw + 256 * k;
    float4 bi = sb[i];
    float ai = sarea[i];
    int c0 = i >> 6;
    u64 myword = 0;
    for (int c = c0; c < 32; ++c) {
      float4 bj = sb[c * 64 + lane];
      float aj = sarea[c * 64 + lane];
      float lx = fmaxf(bi.x, bj.x), ly = fmaxf(bi.y, bj.y);
      float rx = fminf(bi.z, bj.z), ry = fminf(bi.w, bj.w);
      float iw = fmaxf(rx - lx, 0.0f), ih = fmaxf(ry - ly, 0.0f);
      float inter = iw * ih;
      float uni = fmaxf(ai + aj - inter, 1e-9f);
      u64 word = __ballot(inter > 0.5f * uni);
      if (lane == c) myword = word;
    }
    if (lane < 32) mask[((size_t)(b * PRE_K + i)) * 32 + lane] = myword;
  }
}

__global__ __launch_bounds__(64) void k_scan2048(const u64* __restrict__ mask,
                                                 const float4* __restrict__ candOrig,
                                                 const float* __restrict__ candScore,
                                                 const int* __restrict__ candCat,
                                                 const u32* __restrict__ gFlag,
                                                 float* __restrict__ out) {
  int b = blockIdx.x;
  if (gFlag[b]) return;
  int tid = threadIdx.x;
  __shared__ float ssc[PRE_K];
  __shared__ int keptI[MAX_OUT];
  for (int j = tid; j < PRE_K; j += 64) ssc[j] = candScore[b * PRE_K + j];
  __syncthreads();

  const u64* mrow = mask + (size_t)b * PRE_K * 32;
  int wsel = tid & 31;
  bool lo32 = tid < 32;
  u64 remv = 0;
  int cnt = 0;

  u64 c0=0,c1=0,c2=0,c3=0,c4=0,c5=0,c6=0,c7=0;
  if (lo32) {
    c0 = mrow[0 * 32 + wsel]; c1 = mrow[1 * 32 + wsel];
    c2 = mrow[2 * 32 + wsel]; c3 = mrow[3 * 32 + wsel];
    c4 = mrow[4 * 32 + wsel]; c5 = mrow[5 * 32 + wsel];
    c6 = mrow[6 * 32 + wsel]; c7 = mrow[7 * 32 + wsel];
  }

#define PROCESS(I, RK)                                   \
  {                                                      \
    u64 wb = __shfl(remv, (I) >> 6);                     \
    bool sup = (wb >> ((I) & 63)) & 1ull;                \
    if (!sup && ssc[I] > SCORE_TH) {                     \
      if (tid == 0 && cnt < MAX_OUT) keptI[cnt] = (I);   \
      if (lo32) remv |= (RK);                            \
      cnt++;                                             \
    }                                                    \
  }

  for (int base = 0; base < PRE_K; base += 8) {
    u64 n0=0,n1=0,n2=0,n3=0,n4=0,n5=0,n6=0,n7=0;
    if (base + 8 < PRE_K && lo32) {
      const u64* nr = mrow + (size_t)(base + 8) * 32 + wsel;
      n0 = nr[0 * 32]; n1 = nr[1 * 32]; n2 = nr[2 * 32]; n3 = nr[3 * 32];
      n4 = nr[4 * 32]; n5 = nr[5 * 32]; n6 = nr[6 * 32]; n7 = nr[7 * 32];
    }
    PROCESS(base + 0, c0); PROCESS(base + 1, c1);
    PROCESS(base + 2, c2); PROCESS(base + 3, c3);
    PROCESS(base + 4, c4); PROCESS(base + 5, c5);
    PROCESS(base + 6, c6); PROCESS(base + 7, c7);
    c0=n0; c1=n1; c2=n2; c3=n3; c4=n4; c5=n5; c6=n6; c7=n7;
    if (cnt >= MAX_OUT) break;
  }
#undef PROCESS

  int kc = cnt < MAX_OUT ? cnt : MAX_OUT;
  __syncthreads();

  float* out5 = out;
  float* ocat = out + BATCH * MAX_OUT * 5;
  for (int r = tid; r < MAX_OUT; r += 64) {
    float* p = out5 + ((size_t)(b * MAX_OUT + r)) * 5;
    if (r < kc) {
      int i = keptI[r];
      float4 ob = candOrig[b * PRE_K + i];
      p[0] = ob.x; p[1] = ob.y; p[2] = ob.z; p[3] = ob.w; p[4] = ssc[i];
      ocat[b * MAX_OUT + r] = (float)candCat[b * PRE_K + i];
    } else {
      p[0] = 0.0f; p[1] = 0.0f; p[2] = 0.0f; p[3] = 0.0f; p[4] = 0.0f;
      ocat[b * MAX_OUT + r] = 0.0f;
    }
  }
}

extern "C" void kernel_launch(void* const* d_in, const int* in_sizes, int n_in,
                              void* d_out, int out_size, void* d_ws, size_t ws_size,
                              hipStream_t stream) {
  const float* boxes = (const float*)d_in[0];
  const float* confs = (const float*)d_in[1];
  float* out = (float*)d_out;
  char* ws = (char*)d_ws;

  const size_t OFF_KHI  = 0;                            // 1 MB
  const size_t OFF_CATS = (size_t)1 << 20;              // 256 KB
  const size_t OFF_FLAG = OFF_CATS + (256u << 10);      // 64 B
  const size_t OFF_COFF = OFF_FLAG + 1024;              // 256 KB
  const size_t OFF_CORG = OFF_COFF + (256u << 10);      // 256 KB
  const size_t OFF_CSC  = OFF_CORG + (256u << 10);      // 64 KB
  const size_t OFF_CCAT = OFF_CSC + (64u << 10);        // 64 KB
  const size_t OFF_MASK = OFF_CCAT + (64u << 10);       // 4 MB

  u32* keyhi   = (u32*)(ws + OFF_KHI);
  u8* cats     = (u8*)(ws + OFF_CATS);
  u32* gFlag   = (u32*)(ws + OFF_FLAG);
  float4* cOff = (float4*)(ws + OFF_COFF);
  float4* cOrg = (float4*)(ws + OFF_CORG);
  float* cSc   = (float*)(ws + OFF_CSC);
  int* cCat    = (int*)(ws + OFF_CCAT);
  u64* mask    = (u64*)(ws + OFF_MASK);

  k_score<<<BATCH * NANCH / 64, 256, 0, stream>>>(confs, keyhi, cats);
  k_nms256<<<BATCH, 1024, 0, stream>>>(keyhi, cats, boxes, out, gFlag);
  // fallback (exact 2048 path), no-ops when gFlag[b] == 1
  k_sel2048<<<BATCH, 1024, 0, stream>>>(keyhi, cats, boxes, gFlag, cOff, cOrg, cSc, cCat);
  dim3 g3(64, BATCH);
  k_mask2048<<<g3, 256, 0, stream>>>(cOff, gFlag, mask);
  k_scan2048<<<BATCH, 64, 0, stream>>>(mask, cOrg, cSc, cCat, gFlag, out);
}